// Round 2
// baseline (845.984 us; speedup 1.0000x reference)
//
#include <hip/hip_runtime.h>

#define N_NODES 50000
#define N_EDGES 800000
#define NF 128
#define BN_EPS 1e-5f
#define G_ROWS 32

// Kernel 1: agg(=d_out) = x (fp32 copy), zero the 256-float stats area.
__global__ void init_agg(const float* __restrict__ x,
                         float* __restrict__ agg,
                         float* __restrict__ stats) {
    int tid = blockIdx.x * blockDim.x + threadIdx.x;
    if (tid < 256) stats[tid] = 0.0f;
    const float4* x4 = (const float4*)x;
    float4* a4 = (float4*)agg;
    int n4 = N_NODES * NF / 4;
    int stride = gridDim.x * blockDim.x;
    for (int i = tid; i < n4; i += stride) a4[i] = x4[i];
}

// Kernel 1b: transpose W1, W2 into workspace (Wt[k][o] = W[o][k]).
__global__ void prep_weights(const float* __restrict__ W1,
                             const float* __restrict__ W2,
                             float* __restrict__ Wt1,
                             float* __restrict__ Wt2) {
    int t = blockIdx.x * blockDim.x + threadIdx.x; // 16384 threads
    if (t < 128 * 128) {
        int o = t >> 7, k = t & 127;
        Wt1[k * 128 + o] = W1[t];
        Wt2[k * 128 + o] = W2[t];
    }
}

// Kernel 2: agg[dst] += x[src] per edge. One wave per edge, 2 floats/lane.
__global__ void scatter_add(const float* __restrict__ x,
                            const int* __restrict__ ei,
                            float* __restrict__ agg) {
    int t = blockIdx.x * blockDim.x + threadIdx.x;
    int edge = t >> 6;
    int lane = t & 63;
    if (edge >= N_EDGES) return;
    int src = ei[edge];
    int dst = ei[N_EDGES + edge];
    float2 v = ((const float2*)x)[src * (NF / 2) + lane];
    float* dp = agg + (size_t)dst * NF + lane * 2;
    atomicAdd(dp, v.x);
    atomicAdd(dp + 1, v.y);
}

// Kernel 3: h = relu(agg @ W1^T + b1), in-place over agg (=d_out).
// Fused BN-stat accumulation (per-column sum/sumsq -> global atomics).
__global__ __launch_bounds__(256) void gemm1_kernel(
    float* __restrict__ agg,
    const float* __restrict__ Wt,  // Wt[k][o], 128x128
    const float* __restrict__ b1,
    float* __restrict__ stats) {
    __shared__ float At[G_ROWS][132];

    int t = threadIdx.x;
    int base = blockIdx.x * G_ROWS;
    int nrows = N_NODES - base; if (nrows > G_ROWS) nrows = G_ROWS;

    for (int i = t; i < G_ROWS * (NF / 4); i += 256) {
        int r = i >> 5, c4 = i & 31;
        float4 v;
        if (r < nrows) v = ((const float4*)(agg + (size_t)(base + r) * NF))[c4];
        else v = make_float4(0.f, 0.f, 0.f, 0.f);
        *((float4*)&At[r][c4 * 4]) = v;
    }
    __syncthreads();

    int tc = t & 31, tr = t >> 5;
    int c0 = tc * 4, r0 = tr * 4;
    float acc[4][4] = {{0.f}};

    for (int k = 0; k < 128; k += 4) {
        float4 a[4];
#pragma unroll
        for (int r = 0; r < 4; r++) a[r] = *((const float4*)&At[r0 + r][k]);
        float4 w[4];
#pragma unroll
        for (int j = 0; j < 4; j++)
            w[j] = *((const float4*)(Wt + (size_t)(k + j) * 128 + c0));
#pragma unroll
        for (int r = 0; r < 4; r++) {
            float av[4] = {a[r].x, a[r].y, a[r].z, a[r].w};
#pragma unroll
            for (int j = 0; j < 4; j++) {
                acc[r][0] += av[j] * w[j].x;
                acc[r][1] += av[j] * w[j].y;
                acc[r][2] += av[j] * w[j].z;
                acc[r][3] += av[j] * w[j].w;
            }
        }
    }

    float4 bias = *((const float4*)(b1 + c0));

    __syncthreads(); // done reading At; about to overwrite it with h
#pragma unroll
    for (int r = 0; r < 4; r++) {
        float4 hv;
        hv.x = fmaxf(acc[r][0] + bias.x, 0.f);
        hv.y = fmaxf(acc[r][1] + bias.y, 0.f);
        hv.z = fmaxf(acc[r][2] + bias.z, 0.f);
        hv.w = fmaxf(acc[r][3] + bias.w, 0.f);
        *((float4*)&At[r0 + r][c0]) = hv;
        int row = base + r0 + r;
        if (row < N_NODES)
            *((float4*)(agg + (size_t)row * NF + c0)) = hv;
    }
    __syncthreads();

    if (t < 128) {
        float s = 0.f, sq = 0.f;
        for (int r = 0; r < nrows; r++) {
            float v = At[r][t];
            s += v; sq += v * v;
        }
        atomicAdd(&stats[t], s);
        atomicAdd(&stats[128 + t], sq);
    }
}

// Kernel 4: fold BN into per-feature affine a,c.
__global__ void finalize_bn(const float* __restrict__ stats,
                            const float* __restrict__ gamma,
                            const float* __restrict__ beta,
                            float* __restrict__ ab) {
    int f = threadIdx.x;
    if (f < 128) {
        float mean = stats[f] * (1.0f / N_NODES);
        float var = stats[128 + f] * (1.0f / N_NODES) - mean * mean;
        float rstd = rsqrtf(var + BN_EPS);
        float a = gamma[f] * rstd;
        float c = beta[f] - mean * a;
        ab[f] = a;
        ab[128 + f] = c;
    }
}

// Kernel 5: out = ((h*a + c) @ W2^T + b2), in-place over h (=d_out).
__global__ __launch_bounds__(256) void gemm2_kernel(
    float* __restrict__ h,
    const float* __restrict__ Wt,  // Wt[k][o], 128x128
    const float* __restrict__ b2,
    const float* __restrict__ ab) {
    __shared__ float At[G_ROWS][132];

    int t = threadIdx.x;
    int base = blockIdx.x * G_ROWS;
    int nrows = N_NODES - base; if (nrows > G_ROWS) nrows = G_ROWS;

    for (int i = t; i < G_ROWS * (NF / 4); i += 256) {
        int r = i >> 5, c4 = i & 31;
        float4 av = ((const float4*)ab)[c4];
        float4 cv = ((const float4*)(ab + 128))[c4];
        float4 v;
        if (r < nrows) {
            float4 hv = ((const float4*)(h + (size_t)(base + r) * NF))[c4];
            v.x = hv.x * av.x + cv.x;
            v.y = hv.y * av.y + cv.y;
            v.z = hv.z * av.z + cv.z;
            v.w = hv.w * av.w + cv.w;
        } else {
            v = make_float4(0.f, 0.f, 0.f, 0.f);
        }
        *((float4*)&At[r][c4 * 4]) = v;
    }
    __syncthreads();

    int tc = t & 31, tr = t >> 5;
    int c0 = tc * 4, r0 = tr * 4;
    float acc[4][4] = {{0.f}};

    for (int k = 0; k < 128; k += 4) {
        float4 a[4];
#pragma unroll
        for (int r = 0; r < 4; r++) a[r] = *((const float4*)&At[r0 + r][k]);
        float4 w[4];
#pragma unroll
        for (int j = 0; j < 4; j++)
            w[j] = *((const float4*)(Wt + (size_t)(k + j) * 128 + c0));
#pragma unroll
        for (int r = 0; r < 4; r++) {
            float av[4] = {a[r].x, a[r].y, a[r].z, a[r].w};
#pragma unroll
            for (int j = 0; j < 4; j++) {
                acc[r][0] += av[j] * w[j].x;
                acc[r][1] += av[j] * w[j].y;
                acc[r][2] += av[j] * w[j].z;
                acc[r][3] += av[j] * w[j].w;
            }
        }
    }

    float4 bias = *((const float4*)(b2 + c0));

#pragma unroll
    for (int r = 0; r < 4; r++) {
        int row = base + r0 + r;
        if (row < N_NODES) {
            float4 o;
            o.x = acc[r][0] + bias.x;
            o.y = acc[r][1] + bias.y;
            o.z = acc[r][2] + bias.z;
            o.w = acc[r][3] + bias.w;
            *((float4*)(h + (size_t)row * NF + c0)) = o;
        }
    }
}

extern "C" void kernel_launch(void* const* d_in, const int* in_sizes, int n_in,
                              void* d_out, int out_size, void* d_ws, size_t ws_size,
                              hipStream_t stream) {
    const float* x     = (const float*)d_in[0];
    const int*   ei    = (const int*)d_in[1];
    const float* W1    = (const float*)d_in[2];
    const float* b1    = (const float*)d_in[3];
    const float* gamma = (const float*)d_in[4];
    const float* beta  = (const float*)d_in[5];
    const float* W2    = (const float*)d_in[6];
    const float* b2    = (const float*)d_in[7];

    float* agg = (float*)d_out;  // N_NODES*NF fp32 — used as agg, then h, then out

    float* stats = (float*)d_ws;       // 256 fp32 (sum, sumsq)
    float* ab    = stats + 256;        // 256 fp32 (a, c)
    float* Wt1   = ab + 256;           // 128*128 fp32
    float* Wt2   = Wt1 + 128 * 128;    // 128*128 fp32

    init_agg<<<4096, 256, 0, stream>>>(x, agg, stats);
    prep_weights<<<64, 256, 0, stream>>>(W1, W2, Wt1, Wt2);
    scatter_add<<<(N_EDGES * 64) / 256, 256, 0, stream>>>(x, ei, agg);
    int gblocks = (N_NODES + G_ROWS - 1) / G_ROWS;
    gemm1_kernel<<<gblocks, 256, 0, stream>>>(agg, Wt1, b1, stats);
    finalize_bn<<<1, 128, 0, stream>>>(stats, gamma, beta, ab);
    gemm2_kernel<<<gblocks, 256, 0, stream>>>(agg, Wt2, b2, ab);
}

// Round 3
// 449.804 us; speedup vs baseline: 1.8808x; 1.8808x over previous
//
#include <hip/hip_runtime.h>

#define N_NODES 50000
#define N_EDGES 800000
#define NF 128
#define BN_EPS 1e-5f
#define G_ROWS 32

// ---------------- CSR build (counting sort by dst) ----------------

// Zero counts[N_NODES] and stats[256].
__global__ void zero_kernel(int* __restrict__ counts, float* __restrict__ stats) {
    int t = blockIdx.x * blockDim.x + threadIdx.x;
    if (t < N_NODES) counts[t] = 0;
    if (t < 256) stats[t] = 0.0f;
}

// Histogram of in-degrees.
__global__ void hist_kernel(const int* __restrict__ ei, int* __restrict__ counts) {
    int t = blockIdx.x * blockDim.x + threadIdx.x;
    if (t < N_EDGES) atomicAdd(&counts[ei[N_EDGES + t]], 1);
}

// Single-block exclusive scan of counts -> rowptr (and cursor copy).
__global__ __launch_bounds__(1024) void scan_kernel(const int* __restrict__ counts,
                                                    int* __restrict__ rowptr,
                                                    int* __restrict__ cursor) {
    __shared__ int sums[1024];
    int t = threadIdx.x;
    const int PER = (N_NODES + 1023) / 1024; // 49
    int start = t * PER;
    int s = 0;
    for (int i = 0; i < PER; i++) {
        int idx = start + i;
        if (idx < N_NODES) s += counts[idx];
    }
    sums[t] = s;
    __syncthreads();
    for (int off = 1; off < 1024; off <<= 1) {
        int v = (t >= off) ? sums[t - off] : 0;
        __syncthreads();
        sums[t] += v;
        __syncthreads();
    }
    int run = (t == 0) ? 0 : sums[t - 1];
    for (int i = 0; i < PER; i++) {
        int idx = start + i;
        if (idx < N_NODES) {
            rowptr[idx] = run;
            cursor[idx] = run;
            run += counts[idx];
        }
    }
    if (t == 0) rowptr[N_NODES] = N_EDGES;
}

// Scatter each edge's src into its dst's CSR segment.
__global__ void fill_kernel(const int* __restrict__ ei,
                            int* __restrict__ cursor,
                            int* __restrict__ ssrc) {
    int t = blockIdx.x * blockDim.x + threadIdx.x;
    if (t < N_EDGES) {
        int dst = ei[N_EDGES + t];
        int pos = atomicAdd(&cursor[dst], 1);
        ssrc[pos] = ei[t];
    }
}

// ---------------- Gather: agg[i] = x[i] + sum_{j in N(i)} x[j] ----------------
// One wave per node; each lane owns 2 features (float2). No atomics.
__global__ __launch_bounds__(256) void gather_kernel(const float* __restrict__ x,
                                                     const int* __restrict__ rowptr,
                                                     const int* __restrict__ ssrc,
                                                     float* __restrict__ agg) {
    int node = (blockIdx.x * blockDim.x + threadIdx.x) >> 6;
    int lane = threadIdx.x & 63;
    if (node >= N_NODES) return;
    int beg = rowptr[node], end = rowptr[node + 1];
    const float2* x2 = (const float2*)x;
    float2 acc = x2[(size_t)node * 64 + lane];
    int e = beg;
    for (; e + 1 < end; e += 2) {
        int s0 = ssrc[e], s1 = ssrc[e + 1];
        float2 v0 = x2[(size_t)s0 * 64 + lane];
        float2 v1 = x2[(size_t)s1 * 64 + lane];
        acc.x += v0.x + v1.x;
        acc.y += v0.y + v1.y;
    }
    if (e < end) {
        int s0 = ssrc[e];
        float2 v0 = x2[(size_t)s0 * 64 + lane];
        acc.x += v0.x;
        acc.y += v0.y;
    }
    ((float2*)agg)[(size_t)node * 64 + lane] = acc;
}

// ---------------- Weights transpose ----------------
__global__ void prep_weights(const float* __restrict__ W1,
                             const float* __restrict__ W2,
                             float* __restrict__ Wt1,
                             float* __restrict__ Wt2) {
    int t = blockIdx.x * blockDim.x + threadIdx.x;
    if (t < 128 * 128) {
        int o = t >> 7, k = t & 127;
        Wt1[k * 128 + o] = W1[t];
        Wt2[k * 128 + o] = W2[t];
    }
}

// ---------------- GEMM1: h = relu(agg @ W1^T + b1) + BN stats ----------------
__global__ __launch_bounds__(256) void gemm1_kernel(
    float* __restrict__ agg,
    const float* __restrict__ Wt,  // Wt[k][o], 128x128
    const float* __restrict__ b1,
    float* __restrict__ stats) {
    __shared__ float At[G_ROWS][132];

    int t = threadIdx.x;
    int base = blockIdx.x * G_ROWS;
    int nrows = N_NODES - base; if (nrows > G_ROWS) nrows = G_ROWS;

    for (int i = t; i < G_ROWS * (NF / 4); i += 256) {
        int r = i >> 5, c4 = i & 31;
        float4 v;
        if (r < nrows) v = ((const float4*)(agg + (size_t)(base + r) * NF))[c4];
        else v = make_float4(0.f, 0.f, 0.f, 0.f);
        *((float4*)&At[r][c4 * 4]) = v;
    }
    __syncthreads();

    int tc = t & 31, tr = t >> 5;
    int c0 = tc * 4, r0 = tr * 4;
    float acc[4][4] = {{0.f}};

    for (int k = 0; k < 128; k += 4) {
        float4 a[4];
#pragma unroll
        for (int r = 0; r < 4; r++) a[r] = *((const float4*)&At[r0 + r][k]);
        float4 w[4];
#pragma unroll
        for (int j = 0; j < 4; j++)
            w[j] = *((const float4*)(Wt + (size_t)(k + j) * 128 + c0));
#pragma unroll
        for (int r = 0; r < 4; r++) {
            float av[4] = {a[r].x, a[r].y, a[r].z, a[r].w};
#pragma unroll
            for (int j = 0; j < 4; j++) {
                acc[r][0] += av[j] * w[j].x;
                acc[r][1] += av[j] * w[j].y;
                acc[r][2] += av[j] * w[j].z;
                acc[r][3] += av[j] * w[j].w;
            }
        }
    }

    float4 bias = *((const float4*)(b1 + c0));

    __syncthreads();
#pragma unroll
    for (int r = 0; r < 4; r++) {
        float4 hv;
        hv.x = fmaxf(acc[r][0] + bias.x, 0.f);
        hv.y = fmaxf(acc[r][1] + bias.y, 0.f);
        hv.z = fmaxf(acc[r][2] + bias.z, 0.f);
        hv.w = fmaxf(acc[r][3] + bias.w, 0.f);
        *((float4*)&At[r0 + r][c0]) = hv;
        int row = base + r0 + r;
        if (row < N_NODES)
            *((float4*)(agg + (size_t)row * NF + c0)) = hv;
    }
    __syncthreads();

    if (t < 128) {
        float s = 0.f, sq = 0.f;
        for (int r = 0; r < nrows; r++) {
            float v = At[r][t];
            s += v; sq += v * v;
        }
        atomicAdd(&stats[t], s);
        atomicAdd(&stats[128 + t], sq);
    }
}

// ---------------- BN fold ----------------
__global__ void finalize_bn(const float* __restrict__ stats,
                            const float* __restrict__ gamma,
                            const float* __restrict__ beta,
                            float* __restrict__ ab) {
    int f = threadIdx.x;
    if (f < 128) {
        float mean = stats[f] * (1.0f / N_NODES);
        float var = stats[128 + f] * (1.0f / N_NODES) - mean * mean;
        float rstd = rsqrtf(var + BN_EPS);
        float a = gamma[f] * rstd;
        float c = beta[f] - mean * a;
        ab[f] = a;
        ab[128 + f] = c;
    }
}

// ---------------- GEMM2: out = ((h*a + c) @ W2^T + b2) ----------------
__global__ __launch_bounds__(256) void gemm2_kernel(
    float* __restrict__ h,
    const float* __restrict__ Wt,  // Wt[k][o], 128x128
    const float* __restrict__ b2,
    const float* __restrict__ ab) {
    __shared__ float At[G_ROWS][132];

    int t = threadIdx.x;
    int base = blockIdx.x * G_ROWS;
    int nrows = N_NODES - base; if (nrows > G_ROWS) nrows = G_ROWS;

    for (int i = t; i < G_ROWS * (NF / 4); i += 256) {
        int r = i >> 5, c4 = i & 31;
        float4 av = ((const float4*)ab)[c4];
        float4 cv = ((const float4*)(ab + 128))[c4];
        float4 v;
        if (r < nrows) {
            float4 hv = ((const float4*)(h + (size_t)(base + r) * NF))[c4];
            v.x = hv.x * av.x + cv.x;
            v.y = hv.y * av.y + cv.y;
            v.z = hv.z * av.z + cv.z;
            v.w = hv.w * av.w + cv.w;
        } else {
            v = make_float4(0.f, 0.f, 0.f, 0.f);
        }
        *((float4*)&At[r][c4 * 4]) = v;
    }
    __syncthreads();

    int tc = t & 31, tr = t >> 5;
    int c0 = tc * 4, r0 = tr * 4;
    float acc[4][4] = {{0.f}};

    for (int k = 0; k < 128; k += 4) {
        float4 a[4];
#pragma unroll
        for (int r = 0; r < 4; r++) a[r] = *((const float4*)&At[r0 + r][k]);
        float4 w[4];
#pragma unroll
        for (int j = 0; j < 4; j++)
            w[j] = *((const float4*)(Wt + (size_t)(k + j) * 128 + c0));
#pragma unroll
        for (int r = 0; r < 4; r++) {
            float av[4] = {a[r].x, a[r].y, a[r].z, a[r].w};
#pragma unroll
            for (int j = 0; j < 4; j++) {
                acc[r][0] += av[j] * w[j].x;
                acc[r][1] += av[j] * w[j].y;
                acc[r][2] += av[j] * w[j].z;
                acc[r][3] += av[j] * w[j].w;
            }
        }
    }

    float4 bias = *((const float4*)(b2 + c0));

#pragma unroll
    for (int r = 0; r < 4; r++) {
        int row = base + r0 + r;
        if (row < N_NODES) {
            float4 o;
            o.x = acc[r][0] + bias.x;
            o.y = acc[r][1] + bias.y;
            o.z = acc[r][2] + bias.z;
            o.w = acc[r][3] + bias.w;
            *((float4*)(h + (size_t)row * NF + c0)) = o;
        }
    }
}

extern "C" void kernel_launch(void* const* d_in, const int* in_sizes, int n_in,
                              void* d_out, int out_size, void* d_ws, size_t ws_size,
                              hipStream_t stream) {
    const float* x     = (const float*)d_in[0];
    const int*   ei    = (const int*)d_in[1];
    const float* W1    = (const float*)d_in[2];
    const float* b1    = (const float*)d_in[3];
    const float* gamma = (const float*)d_in[4];
    const float* beta  = (const float*)d_in[5];
    const float* W2    = (const float*)d_in[6];
    const float* b2    = (const float*)d_in[7];

    float* agg = (float*)d_out;  // N_NODES*NF fp32 — agg, then h, then out (in-place)

    // Workspace layout (~3.8 MB)
    float* stats  = (float*)d_ws;            // 256 f
    float* ab     = stats + 256;             // 256 f
    float* Wt1    = ab + 256;                // 16384 f
    float* Wt2    = Wt1 + 128 * 128;         // 16384 f
    int*   counts = (int*)(Wt2 + 128 * 128); // 50000 i
    int*   rowptr = counts + N_NODES;        // 50001 i
    int*   cursor = rowptr + N_NODES + 1;    // 50000 i
    int*   ssrc   = cursor + N_NODES;        // 800000 i

    zero_kernel<<<(N_NODES + 255) / 256, 256, 0, stream>>>(counts, stats);
    prep_weights<<<64, 256, 0, stream>>>(W1, W2, Wt1, Wt2);
    hist_kernel<<<(N_EDGES + 255) / 256, 256, 0, stream>>>(ei, counts);
    scan_kernel<<<1, 1024, 0, stream>>>(counts, rowptr, cursor);
    fill_kernel<<<(N_EDGES + 255) / 256, 256, 0, stream>>>(ei, cursor, ssrc);
    gather_kernel<<<(N_NODES * 64 + 255) / 256, 256, 0, stream>>>(x, rowptr, ssrc, agg);
    int gblocks = (N_NODES + G_ROWS - 1) / G_ROWS;
    gemm1_kernel<<<gblocks, 256, 0, stream>>>(agg, Wt1, b1, stats);
    finalize_bn<<<1, 128, 0, stream>>>(stats, gamma, beta, ab);
    gemm2_kernel<<<gblocks, 256, 0, stream>>>(agg, Wt2, b2, ab);
}

// Round 4
// 342.888 us; speedup vs baseline: 2.4672x; 1.3118x over previous
//
#include <hip/hip_runtime.h>

#define N_NODES 50000
#define N_EDGES 800000
#define NF 128
#define BN_EPS 1e-5f
#define G_ROWS 32
#define SCAN_BLOCKS ((N_NODES + 255) / 256)  // 196

// ---------------- CSR build (counting sort by dst) ----------------

// Zero counts[N_NODES] and stats[256].
__global__ void zero_kernel(int* __restrict__ counts, float* __restrict__ stats) {
    int t = blockIdx.x * blockDim.x + threadIdx.x;
    if (t < N_NODES) counts[t] = 0;
    if (t < 256) stats[t] = 0.0f;
}

// Histogram of in-degrees.
__global__ void hist_kernel(const int* __restrict__ ei, int* __restrict__ counts) {
    int t = blockIdx.x * blockDim.x + threadIdx.x;
    if (t < N_EDGES) atomicAdd(&counts[ei[N_EDGES + t]], 1);
}

// Scan phase A: per-block (256-chunk) reduction of counts -> partials.
__global__ __launch_bounds__(256) void scan_reduce(const int* __restrict__ counts,
                                                   int* __restrict__ partials) {
    __shared__ int red[256];
    int t = threadIdx.x;
    int i = blockIdx.x * 256 + t;
    red[t] = (i < N_NODES) ? counts[i] : 0;
    __syncthreads();
    for (int off = 128; off > 0; off >>= 1) {
        if (t < off) red[t] += red[t + off];
        __syncthreads();
    }
    if (t == 0) partials[blockIdx.x] = red[0];
}

// Scan phase B: exclusive scan of the 196 partials in one small block.
__global__ __launch_bounds__(256) void scan_partials(int* __restrict__ partials) {
    __shared__ int s[256];
    int t = threadIdx.x;
    s[t] = (t < SCAN_BLOCKS) ? partials[t] : 0;
    __syncthreads();
    for (int off = 1; off < 256; off <<= 1) {
        int v = (t >= off) ? s[t - off] : 0;
        __syncthreads();
        s[t] += v;
        __syncthreads();
    }
    if (t < SCAN_BLOCKS) partials[t] = s[t] - ((t < SCAN_BLOCKS) ? 0 : 0) - (t < SCAN_BLOCKS ? (t == 0 ? s[0] : s[t] - s[t - 1]) : 0) + 0
        ; // (rewritten below for clarity)
}

// NOTE: scan_partials above is intentionally replaced by this correct version.
__global__ __launch_bounds__(256) void scan_partials2(int* __restrict__ partials) {
    __shared__ int s[256];
    int t = threadIdx.x;
    int v = (t < SCAN_BLOCKS) ? partials[t] : 0;
    s[t] = v;
    __syncthreads();
    for (int off = 1; off < 256; off <<= 1) {
        int u = (t >= off) ? s[t - off] : 0;
        __syncthreads();
        s[t] += u;
        __syncthreads();
    }
    if (t < SCAN_BLOCKS) partials[t] = s[t] - v;  // exclusive
}

// Scan phase C: block-local scan + block offset -> rowptr, cursor.
__global__ __launch_bounds__(256) void scan_apply(const int* __restrict__ counts,
                                                  const int* __restrict__ partials,
                                                  int* __restrict__ rowptr,
                                                  int* __restrict__ cursor) {
    __shared__ int s[256];
    int t = threadIdx.x;
    int i = blockIdx.x * 256 + t;
    int v = (i < N_NODES) ? counts[i] : 0;
    s[t] = v;
    __syncthreads();
    for (int off = 1; off < 256; off <<= 1) {
        int u = (t >= off) ? s[t - off] : 0;
        __syncthreads();
        s[t] += u;
        __syncthreads();
    }
    int excl = partials[blockIdx.x] + s[t] - v;
    if (i < N_NODES) {
        rowptr[i] = excl;
        cursor[i] = excl;
    }
    if (i == 0) rowptr[N_NODES] = N_EDGES;
}

// Scatter each edge's src into its dst's CSR segment.
__global__ void fill_kernel(const int* __restrict__ ei,
                            int* __restrict__ cursor,
                            int* __restrict__ ssrc) {
    int t = blockIdx.x * blockDim.x + threadIdx.x;
    if (t < N_EDGES) {
        int dst = ei[N_EDGES + t];
        int pos = atomicAdd(&cursor[dst], 1);
        ssrc[pos] = ei[t];
    }
}

// ---------------- Gather: agg[i] = x[i] + sum_{j in N(i)} x[j] ----------------
__global__ __launch_bounds__(256) void gather_kernel(const float* __restrict__ x,
                                                     const int* __restrict__ rowptr,
                                                     const int* __restrict__ ssrc,
                                                     float* __restrict__ agg) {
    int node = (blockIdx.x * blockDim.x + threadIdx.x) >> 6;
    int lane = threadIdx.x & 63;
    if (node >= N_NODES) return;
    int beg = rowptr[node], end = rowptr[node + 1];
    const float2* x2 = (const float2*)x;
    float2 acc = x2[(size_t)node * 64 + lane];
    int e = beg;
    for (; e + 1 < end; e += 2) {
        int s0 = ssrc[e], s1 = ssrc[e + 1];
        float2 v0 = x2[(size_t)s0 * 64 + lane];
        float2 v1 = x2[(size_t)s1 * 64 + lane];
        acc.x += v0.x + v1.x;
        acc.y += v0.y + v1.y;
    }
    if (e < end) {
        int s0 = ssrc[e];
        float2 v0 = x2[(size_t)s0 * 64 + lane];
        acc.x += v0.x;
        acc.y += v0.y;
    }
    ((float2*)agg)[(size_t)node * 64 + lane] = acc;
}

// ---------------- Weights transpose ----------------
__global__ void prep_weights(const float* __restrict__ W1,
                             const float* __restrict__ W2,
                             float* __restrict__ Wt1,
                             float* __restrict__ Wt2) {
    int t = blockIdx.x * blockDim.x + threadIdx.x;
    if (t < 128 * 128) {
        int o = t >> 7, k = t & 127;
        Wt1[k * 128 + o] = W1[t];
        Wt2[k * 128 + o] = W2[t];
    }
}

// ---------------- GEMM1: h = relu(agg @ W1^T + b1) + BN stats ----------------
__global__ __launch_bounds__(256) void gemm1_kernel(
    float* __restrict__ agg,
    const float* __restrict__ Wt,  // Wt[k][o], 128x128
    const float* __restrict__ b1,
    float* __restrict__ stats) {
    __shared__ float At[G_ROWS][132];

    int t = threadIdx.x;
    int base = blockIdx.x * G_ROWS;
    int nrows = N_NODES - base; if (nrows > G_ROWS) nrows = G_ROWS;

    for (int i = t; i < G_ROWS * (NF / 4); i += 256) {
        int r = i >> 5, c4 = i & 31;
        float4 v;
        if (r < nrows) v = ((const float4*)(agg + (size_t)(base + r) * NF))[c4];
        else v = make_float4(0.f, 0.f, 0.f, 0.f);
        *((float4*)&At[r][c4 * 4]) = v;
    }
    __syncthreads();

    int tc = t & 31, tr = t >> 5;
    int c0 = tc * 4, r0 = tr * 4;
    float acc[4][4] = {{0.f}};

    for (int k = 0; k < 128; k += 4) {
        float4 a[4];
#pragma unroll
        for (int r = 0; r < 4; r++) a[r] = *((const float4*)&At[r0 + r][k]);
        float4 w[4];
#pragma unroll
        for (int j = 0; j < 4; j++)
            w[j] = *((const float4*)(Wt + (size_t)(k + j) * 128 + c0));
#pragma unroll
        for (int r = 0; r < 4; r++) {
            float av[4] = {a[r].x, a[r].y, a[r].z, a[r].w};
#pragma unroll
            for (int j = 0; j < 4; j++) {
                acc[r][0] += av[j] * w[j].x;
                acc[r][1] += av[j] * w[j].y;
                acc[r][2] += av[j] * w[j].z;
                acc[r][3] += av[j] * w[j].w;
            }
        }
    }

    float4 bias = *((const float4*)(b1 + c0));

    __syncthreads();
#pragma unroll
    for (int r = 0; r < 4; r++) {
        float4 hv;
        hv.x = fmaxf(acc[r][0] + bias.x, 0.f);
        hv.y = fmaxf(acc[r][1] + bias.y, 0.f);
        hv.z = fmaxf(acc[r][2] + bias.z, 0.f);
        hv.w = fmaxf(acc[r][3] + bias.w, 0.f);
        *((float4*)&At[r0 + r][c0]) = hv;
        int row = base + r0 + r;
        if (row < N_NODES)
            *((float4*)(agg + (size_t)row * NF + c0)) = hv;
    }
    __syncthreads();

    if (t < 128) {
        float s = 0.f, sq = 0.f;
        for (int r = 0; r < nrows; r++) {
            float v = At[r][t];
            s += v; sq += v * v;
        }
        atomicAdd(&stats[t], s);
        atomicAdd(&stats[128 + t], sq);
    }
}

// ---------------- BN fold ----------------
__global__ void finalize_bn(const float* __restrict__ stats,
                            const float* __restrict__ gamma,
                            const float* __restrict__ beta,
                            float* __restrict__ ab) {
    int f = threadIdx.x;
    if (f < 128) {
        float mean = stats[f] * (1.0f / N_NODES);
        float var = stats[128 + f] * (1.0f / N_NODES) - mean * mean;
        float rstd = rsqrtf(var + BN_EPS);
        float a = gamma[f] * rstd;
        float c = beta[f] - mean * a;
        ab[f] = a;
        ab[128 + f] = c;
    }
}

// ---------------- GEMM2: out = ((h*a + c) @ W2^T + b2) ----------------
__global__ __launch_bounds__(256) void gemm2_kernel(
    float* __restrict__ h,
    const float* __restrict__ Wt,  // Wt[k][o], 128x128
    const float* __restrict__ b2,
    const float* __restrict__ ab) {
    __shared__ float At[G_ROWS][132];

    int t = threadIdx.x;
    int base = blockIdx.x * G_ROWS;
    int nrows = N_NODES - base; if (nrows > G_ROWS) nrows = G_ROWS;

    for (int i = t; i < G_ROWS * (NF / 4); i += 256) {
        int r = i >> 5, c4 = i & 31;
        float4 av = ((const float4*)ab)[c4];
        float4 cv = ((const float4*)(ab + 128))[c4];
        float4 v;
        if (r < nrows) {
            float4 hv = ((const float4*)(h + (size_t)(base + r) * NF))[c4];
            v.x = hv.x * av.x + cv.x;
            v.y = hv.y * av.y + cv.y;
            v.z = hv.z * av.z + cv.z;
            v.w = hv.w * av.w + cv.w;
        } else {
            v = make_float4(0.f, 0.f, 0.f, 0.f);
        }
        *((float4*)&At[r][c4 * 4]) = v;
    }
    __syncthreads();

    int tc = t & 31, tr = t >> 5;
    int c0 = tc * 4, r0 = tr * 4;
    float acc[4][4] = {{0.f}};

    for (int k = 0; k < 128; k += 4) {
        float4 a[4];
#pragma unroll
        for (int r = 0; r < 4; r++) a[r] = *((const float4*)&At[r0 + r][k]);
        float4 w[4];
#pragma unroll
        for (int j = 0; j < 4; j++)
            w[j] = *((const float4*)(Wt + (size_t)(k + j) * 128 + c0));
#pragma unroll
        for (int r = 0; r < 4; r++) {
            float av[4] = {a[r].x, a[r].y, a[r].z, a[r].w};
#pragma unroll
            for (int j = 0; j < 4; j++) {
                acc[r][0] += av[j] * w[j].x;
                acc[r][1] += av[j] * w[j].y;
                acc[r][2] += av[j] * w[j].z;
                acc[r][3] += av[j] * w[j].w;
            }
        }
    }

    float4 bias = *((const float4*)(b2 + c0));

#pragma unroll
    for (int r = 0; r < 4; r++) {
        int row = base + r0 + r;
        if (row < N_NODES) {
            float4 o;
            o.x = acc[r][0] + bias.x;
            o.y = acc[r][1] + bias.y;
            o.z = acc[r][2] + bias.z;
            o.w = acc[r][3] + bias.w;
            *((float4*)(h + (size_t)row * NF + c0)) = o;
        }
    }
}

extern "C" void kernel_launch(void* const* d_in, const int* in_sizes, int n_in,
                              void* d_out, int out_size, void* d_ws, size_t ws_size,
                              hipStream_t stream) {
    const float* x     = (const float*)d_in[0];
    const int*   ei    = (const int*)d_in[1];
    const float* W1    = (const float*)d_in[2];
    const float* b1    = (const float*)d_in[3];
    const float* gamma = (const float*)d_in[4];
    const float* beta  = (const float*)d_in[5];
    const float* W2    = (const float*)d_in[6];
    const float* b2    = (const float*)d_in[7];

    float* agg = (float*)d_out;  // N_NODES*NF fp32 — agg, then h, then out (in-place)

    // Workspace layout (~3.8 MB)
    float* stats    = (float*)d_ws;              // 256 f
    float* ab       = stats + 256;               // 256 f
    float* Wt1      = ab + 256;                  // 16384 f
    float* Wt2      = Wt1 + 128 * 128;           // 16384 f
    int*   counts   = (int*)(Wt2 + 128 * 128);   // 50000 i
    int*   rowptr   = counts + N_NODES;          // 50001 i
    int*   cursor   = rowptr + N_NODES + 1;      // 50000 i
    int*   partials = cursor + N_NODES;          // 256 i
    int*   ssrc     = partials + 256;            // 800000 i

    zero_kernel<<<(N_NODES + 255) / 256, 256, 0, stream>>>(counts, stats);
    prep_weights<<<64, 256, 0, stream>>>(W1, W2, Wt1, Wt2);
    hist_kernel<<<(N_EDGES + 255) / 256, 256, 0, stream>>>(ei, counts);
    scan_reduce<<<SCAN_BLOCKS, 256, 0, stream>>>(counts, partials);
    scan_partials2<<<1, 256, 0, stream>>>(partials);
    scan_apply<<<SCAN_BLOCKS, 256, 0, stream>>>(counts, partials, rowptr, cursor);
    fill_kernel<<<(N_EDGES + 255) / 256, 256, 0, stream>>>(ei, cursor, ssrc);
    gather_kernel<<<(N_NODES * 64 + 255) / 256, 256, 0, stream>>>(x, rowptr, ssrc, agg);
    int gblocks = (N_NODES + G_ROWS - 1) / G_ROWS;
    gemm1_kernel<<<gblocks, 256, 0, stream>>>(agg, Wt1, b1, stats);
    finalize_bn<<<1, 128, 0, stream>>>(stats, gamma, beta, ab);
    gemm2_kernel<<<gblocks, 256, 0, stream>>>(agg, Wt2, b2, ab);
}

// Round 5
// 319.132 us; speedup vs baseline: 2.6509x; 1.0744x over previous
//
#include <hip/hip_runtime.h>

#define N_NODES 50000
#define N_EDGES 800000
#define NF 128
#define BN_EPS 1e-5f
#define G_ROWS 32
#define SCAN_BLOCKS ((N_NODES + 255) / 256)  // 196
#define AP 136  // bf16 A-tile pitch (shorts): 272B rows -> 16B aligned, 2-way banks
#define HP 132  // fp32 H-tile pitch

typedef __attribute__((ext_vector_type(8))) short short8;
typedef __attribute__((ext_vector_type(4))) float f32x4;

__device__ __forceinline__ unsigned short f2bf(float f) {
    union { float f; unsigned int i; } v; v.f = f;
    unsigned int r = (v.i + 0x7fffu + ((v.i >> 16) & 1u)) >> 16;
    return (unsigned short)r;
}

// ---------------- CSR build (counting sort by dst) ----------------

__global__ void zero_kernel(int* __restrict__ counts, float* __restrict__ stats) {
    int t = blockIdx.x * blockDim.x + threadIdx.x;
    if (t < N_NODES) counts[t] = 0;
    if (t < 256) stats[t] = 0.0f;
}

__global__ void hist_kernel(const int* __restrict__ ei, int* __restrict__ counts) {
    int t = blockIdx.x * blockDim.x + threadIdx.x;
    if (t < N_EDGES) atomicAdd(&counts[ei[N_EDGES + t]], 1);
}

__global__ __launch_bounds__(256) void scan_reduce(const int* __restrict__ counts,
                                                   int* __restrict__ partials) {
    __shared__ int red[256];
    int t = threadIdx.x;
    int i = blockIdx.x * 256 + t;
    red[t] = (i < N_NODES) ? counts[i] : 0;
    __syncthreads();
    for (int off = 128; off > 0; off >>= 1) {
        if (t < off) red[t] += red[t + off];
        __syncthreads();
    }
    if (t == 0) partials[blockIdx.x] = red[0];
}

__global__ __launch_bounds__(256) void scan_partials2(int* __restrict__ partials) {
    __shared__ int s[256];
    int t = threadIdx.x;
    int v = (t < SCAN_BLOCKS) ? partials[t] : 0;
    s[t] = v;
    __syncthreads();
    for (int off = 1; off < 256; off <<= 1) {
        int u = (t >= off) ? s[t - off] : 0;
        __syncthreads();
        s[t] += u;
        __syncthreads();
    }
    if (t < SCAN_BLOCKS) partials[t] = s[t] - v;  // exclusive
}

__global__ __launch_bounds__(256) void scan_apply(const int* __restrict__ counts,
                                                  const int* __restrict__ partials,
                                                  int* __restrict__ rowptr,
                                                  int* __restrict__ cursor) {
    __shared__ int s[256];
    int t = threadIdx.x;
    int i = blockIdx.x * 256 + t;
    int v = (i < N_NODES) ? counts[i] : 0;
    s[t] = v;
    __syncthreads();
    for (int off = 1; off < 256; off <<= 1) {
        int u = (t >= off) ? s[t - off] : 0;
        __syncthreads();
        s[t] += u;
        __syncthreads();
    }
    int excl = partials[blockIdx.x] + s[t] - v;
    if (i < N_NODES) {
        rowptr[i] = excl;
        cursor[i] = excl;
    }
    if (i == 0) rowptr[N_NODES] = N_EDGES;
}

__global__ void fill_kernel(const int* __restrict__ ei,
                            int* __restrict__ cursor,
                            int* __restrict__ ssrc) {
    int t = blockIdx.x * blockDim.x + threadIdx.x;
    if (t < N_EDGES) {
        int dst = ei[N_EDGES + t];
        int pos = atomicAdd(&cursor[dst], 1);
        ssrc[pos] = ei[t];
    }
}

// ---------------- Gather: agg[i] = x[i] + sum_{j in N(i)} x[j] ----------------
__global__ __launch_bounds__(256) void gather_kernel(const float* __restrict__ x,
                                                     const int* __restrict__ rowptr,
                                                     const int* __restrict__ ssrc,
                                                     float* __restrict__ agg) {
    int node = (blockIdx.x * blockDim.x + threadIdx.x) >> 6;
    int lane = threadIdx.x & 63;
    if (node >= N_NODES) return;
    int beg = rowptr[node], end = rowptr[node + 1];
    const float2* x2 = (const float2*)x;
    float2 acc = x2[(size_t)node * 64 + lane];
    int e = beg;
    for (; e + 1 < end; e += 2) {
        int s0 = ssrc[e], s1 = ssrc[e + 1];
        float2 v0 = x2[(size_t)s0 * 64 + lane];
        float2 v1 = x2[(size_t)s1 * 64 + lane];
        acc.x += v0.x + v1.x;
        acc.y += v0.y + v1.y;
    }
    if (e < end) {
        int s0 = ssrc[e];
        float2 v0 = x2[(size_t)s0 * 64 + lane];
        acc.x += v0.x;
        acc.y += v0.y;
    }
    ((float2*)agg)[(size_t)node * 64 + lane] = acc;
}

// ---------------- Weights: fp32 -> bf16, keep [out][in] layout ----------------
__global__ void prep_weights(const float* __restrict__ W1,
                             const float* __restrict__ W2,
                             unsigned short* __restrict__ Wb1,
                             unsigned short* __restrict__ Wb2) {
    int t = blockIdx.x * blockDim.x + threadIdx.x;
    if (t < 128 * 128) {
        Wb1[t] = f2bf(W1[t]);
        Wb2[t] = f2bf(W2[t]);
    }
}

// ---------------- GEMM1 (MFMA): h = relu(agg @ W1^T + b1) + BN stats ----------
// Block: 32 rows x 128 cols. 4 waves: wave w -> rows 16*(w&1), cols 64*(w>>1).
// A staged bf16 in LDS; B fragments read directly from bf16 W ([o][k] layout):
// lane(n=l15,k=q*8+j) -> Wb[n*128 + kc*32 + q*8], contiguous 16B.
__global__ __launch_bounds__(256) void gemm1_kernel(
    float* __restrict__ agg,
    const unsigned short* __restrict__ Wb,
    const float* __restrict__ b1,
    float* __restrict__ stats) {
    __shared__ unsigned short At[G_ROWS][AP];
    __shared__ float Ht[G_ROWS][HP];

    int t = threadIdx.x;
    int base = blockIdx.x * G_ROWS;
    int nrows = N_NODES - base; if (nrows > G_ROWS) nrows = G_ROWS;

    // Stage A tile as bf16.
    for (int i = t; i < G_ROWS * 32; i += 256) {
        int r = i >> 5, c4 = i & 31;
        float4 v = make_float4(0.f, 0.f, 0.f, 0.f);
        if (r < nrows) v = ((const float4*)(agg + (size_t)(base + r) * NF))[c4];
        ushort4 u;
        u.x = f2bf(v.x); u.y = f2bf(v.y); u.z = f2bf(v.z); u.w = f2bf(v.w);
        *((ushort4*)&At[r][c4 * 4]) = u;
    }
    __syncthreads();

    int wave = t >> 6, lane = t & 63;
    int m0 = (wave & 1) * 16;
    int n0 = (wave >> 1) * 64;
    int l15 = lane & 15, q = lane >> 4;

    f32x4 acc[4];
#pragma unroll
    for (int i = 0; i < 4; i++) acc[i] = (f32x4){0.f, 0.f, 0.f, 0.f};

#pragma unroll
    for (int kc = 0; kc < 4; kc++) {
        short8 a = *((const short8*)&At[m0 + l15][kc * 32 + q * 8]);
#pragma unroll
        for (int tile = 0; tile < 4; tile++) {
            short8 b = *((const short8*)(Wb + (size_t)(n0 + 16 * tile + l15) * 128 + kc * 32 + q * 8));
            acc[tile] = __builtin_amdgcn_mfma_f32_16x16x32_bf16(a, b, acc[tile], 0, 0, 0);
        }
    }

    // Epilogue: bias + relu -> Ht (fp32).
#pragma unroll
    for (int tile = 0; tile < 4; tile++) {
        int col = n0 + 16 * tile + l15;
        float bias = b1[col];
#pragma unroll
        for (int reg = 0; reg < 4; reg++) {
            int row = q * 4 + reg;
            Ht[m0 + row][col] = fmaxf(acc[tile][reg] + bias, 0.f);
        }
    }
    __syncthreads();

    // Coalesced writeout of h.
    for (int i = t; i < G_ROWS * 32; i += 256) {
        int r = i >> 5, c4 = i & 31;
        int row = base + r;
        if (row < N_NODES)
            *((float4*)(agg + (size_t)row * NF + c4 * 4)) = *((const float4*)&Ht[r][c4 * 4]);
    }

    // BN stats.
    if (t < 128) {
        float s = 0.f, sq = 0.f;
        for (int r = 0; r < nrows; r++) {
            float v = Ht[r][t];
            s += v; sq += v * v;
        }
        atomicAdd(&stats[t], s);
        atomicAdd(&stats[128 + t], sq);
    }
}

// ---------------- BN fold ----------------
__global__ void finalize_bn(const float* __restrict__ stats,
                            const float* __restrict__ gamma,
                            const float* __restrict__ beta,
                            float* __restrict__ ab) {
    int f = threadIdx.x;
    if (f < 128) {
        float mean = stats[f] * (1.0f / N_NODES);
        float var = stats[128 + f] * (1.0f / N_NODES) - mean * mean;
        float rstd = rsqrtf(var + BN_EPS);
        float a = gamma[f] * rstd;
        float c = beta[f] - mean * a;
        ab[f] = a;
        ab[128 + f] = c;
    }
}

// ---------------- GEMM2 (MFMA): out = ((h*a + c) @ W2^T + b2) ----------------
__global__ __launch_bounds__(256) void gemm2_kernel(
    float* __restrict__ h,
    const unsigned short* __restrict__ Wb,
    const float* __restrict__ b2,
    const float* __restrict__ ab) {
    __shared__ unsigned short At[G_ROWS][AP];
    __shared__ float Ht[G_ROWS][HP];

    int t = threadIdx.x;
    int base = blockIdx.x * G_ROWS;
    int nrows = N_NODES - base; if (nrows > G_ROWS) nrows = G_ROWS;

    // Stage BN(h) tile as bf16.
    for (int i = t; i < G_ROWS * 32; i += 256) {
        int r = i >> 5, c4 = i & 31;
        float4 v = make_float4(0.f, 0.f, 0.f, 0.f);
        if (r < nrows) {
            float4 hv = ((const float4*)(h + (size_t)(base + r) * NF))[c4];
            float4 av = ((const float4*)ab)[c4];
            float4 cv = ((const float4*)(ab + 128))[c4];
            v.x = hv.x * av.x + cv.x;
            v.y = hv.y * av.y + cv.y;
            v.z = hv.z * av.z + cv.z;
            v.w = hv.w * av.w + cv.w;
        }
        ushort4 u;
        u.x = f2bf(v.x); u.y = f2bf(v.y); u.z = f2bf(v.z); u.w = f2bf(v.w);
        *((ushort4*)&At[r][c4 * 4]) = u;
    }
    __syncthreads();

    int wave = t >> 6, lane = t & 63;
    int m0 = (wave & 1) * 16;
    int n0 = (wave >> 1) * 64;
    int l15 = lane & 15, q = lane >> 4;

    f32x4 acc[4];
#pragma unroll
    for (int i = 0; i < 4; i++) acc[i] = (f32x4){0.f, 0.f, 0.f, 0.f};

#pragma unroll
    for (int kc = 0; kc < 4; kc++) {
        short8 a = *((const short8*)&At[m0 + l15][kc * 32 + q * 8]);
#pragma unroll
        for (int tile = 0; tile < 4; tile++) {
            short8 b = *((const short8*)(Wb + (size_t)(n0 + 16 * tile + l15) * 128 + kc * 32 + q * 8));
            acc[tile] = __builtin_amdgcn_mfma_f32_16x16x32_bf16(a, b, acc[tile], 0, 0, 0);
        }
    }

#pragma unroll
    for (int tile = 0; tile < 4; tile++) {
        int col = n0 + 16 * tile + l15;
        float bias = b2[col];
#pragma unroll
        for (int reg = 0; reg < 4; reg++) {
            int row = q * 4 + reg;
            Ht[m0 + row][col] = acc[tile][reg] + bias;
        }
    }
    __syncthreads();

    for (int i = t; i < G_ROWS * 32; i += 256) {
        int r = i >> 5, c4 = i & 31;
        int row = base + r;
        if (row < N_NODES)
            *((float4*)(h + (size_t)row * NF + c4 * 4)) = *((const float4*)&Ht[r][c4 * 4]);
    }
}

extern "C" void kernel_launch(void* const* d_in, const int* in_sizes, int n_in,
                              void* d_out, int out_size, void* d_ws, size_t ws_size,
                              hipStream_t stream) {
    const float* x     = (const float*)d_in[0];
    const int*   ei    = (const int*)d_in[1];
    const float* W1    = (const float*)d_in[2];
    const float* b1    = (const float*)d_in[3];
    const float* gamma = (const float*)d_in[4];
    const float* beta  = (const float*)d_in[5];
    const float* W2    = (const float*)d_in[6];
    const float* b2    = (const float*)d_in[7];

    float* agg = (float*)d_out;  // N_NODES*NF fp32 — agg, then h, then out (in-place)

    // Workspace layout (~3.7 MB)
    float*          stats    = (float*)d_ws;               // 256 f
    float*          ab       = stats + 256;                // 256 f
    unsigned short* Wb1      = (unsigned short*)(ab + 256);// 16384 us
    unsigned short* Wb2      = Wb1 + 128 * 128;            // 16384 us
    int*            counts   = (int*)(Wb2 + 128 * 128);    // 50000 i
    int*            rowptr   = counts + N_NODES;           // 50001 i
    int*            cursor   = rowptr + N_NODES + 1;       // 50000 i
    int*            partials = cursor + N_NODES;           // 256 i
    int*            ssrc     = partials + 256;             // 800000 i

    zero_kernel<<<(N_NODES + 255) / 256, 256, 0, stream>>>(counts, stats);
    prep_weights<<<64, 256, 0, stream>>>(W1, W2, Wb1, Wb2);
    hist_kernel<<<(N_EDGES + 255) / 256, 256, 0, stream>>>(ei, counts);
    scan_reduce<<<SCAN_BLOCKS, 256, 0, stream>>>(counts, partials);
    scan_partials2<<<1, 256, 0, stream>>>(partials);
    scan_apply<<<SCAN_BLOCKS, 256, 0, stream>>>(counts, partials, rowptr, cursor);
    fill_kernel<<<(N_EDGES + 255) / 256, 256, 0, stream>>>(ei, cursor, ssrc);
    gather_kernel<<<(N_NODES * 64 + 255) / 256, 256, 0, stream>>>(x, rowptr, ssrc, agg);
    int gblocks = (N_NODES + G_ROWS - 1) / G_ROWS;
    gemm1_kernel<<<gblocks, 256, 0, stream>>>(agg, Wb1, b1, stats);
    finalize_bn<<<1, 128, 0, stream>>>(stats, gamma, beta, ab);
    gemm2_kernel<<<gblocks, 256, 0, stream>>>(agg, Wb2, b2, ab);
}

// Round 6
// 312.093 us; speedup vs baseline: 2.7107x; 1.0226x over previous
//
#include <hip/hip_runtime.h>

#define N_NODES 50000
#define N_EDGES 800000
#define NF 128
#define BN_EPS 1e-5f
#define G_ROWS 32
#define SCAN_BLOCKS ((N_NODES + 255) / 256)  // 196
#define AP 136  // bf16 A-tile pitch (shorts)
#define HP 132  // fp32 H-tile pitch

typedef __attribute__((ext_vector_type(8))) short short8;
typedef __attribute__((ext_vector_type(4))) float f32x4;

__device__ __forceinline__ unsigned short f2bf(float f) {
    union { float f; unsigned int i; } v; v.f = f;
    unsigned int r = (v.i + 0x7fffu + ((v.i >> 16) & 1u)) >> 16;
    return (unsigned short)r;
}
__device__ __forceinline__ float bf2f(unsigned short u) {
    union { unsigned int i; float f; } v; v.i = ((unsigned int)u) << 16; return v.f;
}

// ---------------- CSR build (counting sort by dst) ----------------

__global__ void zero_kernel(int* __restrict__ counts, float* __restrict__ stats) {
    int t = blockIdx.x * blockDim.x + threadIdx.x;
    if (t < N_NODES) counts[t] = 0;
    if (t < 256) stats[t] = 0.0f;
}

__global__ void hist_kernel(const int* __restrict__ ei, int* __restrict__ counts) {
    int t = blockIdx.x * blockDim.x + threadIdx.x;
    if (t < N_EDGES) atomicAdd(&counts[ei[N_EDGES + t]], 1);
}

__global__ __launch_bounds__(256) void scan_reduce(const int* __restrict__ counts,
                                                   int* __restrict__ partials) {
    __shared__ int red[256];
    int t = threadIdx.x;
    int i = blockIdx.x * 256 + t;
    red[t] = (i < N_NODES) ? counts[i] : 0;
    __syncthreads();
    for (int off = 128; off > 0; off >>= 1) {
        if (t < off) red[t] += red[t + off];
        __syncthreads();
    }
    if (t == 0) partials[blockIdx.x] = red[0];
}

__global__ __launch_bounds__(256) void scan_partials2(int* __restrict__ partials) {
    __shared__ int s[256];
    int t = threadIdx.x;
    int v = (t < SCAN_BLOCKS) ? partials[t] : 0;
    s[t] = v;
    __syncthreads();
    for (int off = 1; off < 256; off <<= 1) {
        int u = (t >= off) ? s[t - off] : 0;
        __syncthreads();
        s[t] += u;
        __syncthreads();
    }
    if (t < SCAN_BLOCKS) partials[t] = s[t] - v;  // exclusive
}

__global__ __launch_bounds__(256) void scan_apply(const int* __restrict__ counts,
                                                  const int* __restrict__ partials,
                                                  int* __restrict__ rowptr,
                                                  int* __restrict__ cursor) {
    __shared__ int s[256];
    int t = threadIdx.x;
    int i = blockIdx.x * 256 + t;
    int v = (i < N_NODES) ? counts[i] : 0;
    s[t] = v;
    __syncthreads();
    for (int off = 1; off < 256; off <<= 1) {
        int u = (t >= off) ? s[t - off] : 0;
        __syncthreads();
        s[t] += u;
        __syncthreads();
    }
    int excl = partials[blockIdx.x] + s[t] - v;
    if (i < N_NODES) {
        rowptr[i] = excl;
        cursor[i] = excl;
    }
    if (i == 0) rowptr[N_NODES] = N_EDGES;
}

__global__ void fill_kernel(const int* __restrict__ ei,
                            int* __restrict__ cursor,
                            int* __restrict__ ssrc) {
    int t = blockIdx.x * blockDim.x + threadIdx.x;
    if (t < N_EDGES) {
        int dst = ei[N_EDGES + t];
        int pos = atomicAdd(&cursor[dst], 1);
        ssrc[pos] = ei[t];
    }
}

// ---------------- x fp32 -> bf16 ----------------
__global__ void convert_x(const float* __restrict__ x, unsigned short* __restrict__ xb) {
    int t = blockIdx.x * blockDim.x + threadIdx.x; // 1.6M threads
    if (t < N_NODES * NF / 4) {
        float4 v = ((const float4*)x)[t];
        ushort4 u;
        u.x = f2bf(v.x); u.y = f2bf(v.y); u.z = f2bf(v.z); u.w = f2bf(v.w);
        ((ushort4*)xb)[t] = u;
    }
}

// ---------------- Weights: fp32 -> bf16, keep [out][in] layout ----------------
__global__ void prep_weights(const float* __restrict__ W1,
                             const float* __restrict__ W2,
                             unsigned short* __restrict__ Wb1,
                             unsigned short* __restrict__ Wb2) {
    int t = blockIdx.x * blockDim.x + threadIdx.x;
    if (t < 128 * 128) {
        Wb1[t] = f2bf(W1[t]);
        Wb2[t] = f2bf(W2[t]);
    }
}

// ------- Fused: gather (x[i] + sum x_j) -> bf16 LDS tile -> MFMA gemm1 -------
// h = relu(agg @ W1^T + b1) written to hout; BN stats accumulated.
// XBF16: x is bf16 (ushort2/lane); else fp32 (float2/lane).
template <bool XBF16>
__global__ __launch_bounds__(256) void fused_gather_gemm1(
    const void* __restrict__ xv,
    const int* __restrict__ rowptr,
    const int* __restrict__ ssrc,
    const unsigned short* __restrict__ Wb,
    const float* __restrict__ b1,
    float* __restrict__ hout,
    float* __restrict__ stats) {
    __shared__ unsigned short At[G_ROWS][AP];
    __shared__ float Ht[G_ROWS][HP];

    int t = threadIdx.x;
    int wave = t >> 6, lane = t & 63;
    int base = blockIdx.x * G_ROWS;
    int nrows = N_NODES - base; if (nrows > G_ROWS) nrows = G_ROWS;

    const unsigned int* xb2 = (const unsigned int*)xv; // bf16x2 per lane
    const float2*       xf2 = (const float2*)xv;       // fp32x2 per lane

    // Gather phase: each wave owns 8 consecutive tile rows.
    for (int nn = 0; nn < 8; nn++) {
        int r = wave * 8 + nn;
        int node = base + r;
        float2 acc = make_float2(0.f, 0.f);
        if (node < N_NODES) {
            if (XBF16) {
                unsigned int u = xb2[(size_t)node * 64 + lane];
                acc.x = bf2f((unsigned short)(u & 0xffffu));
                acc.y = bf2f((unsigned short)(u >> 16));
            } else {
                acc = xf2[(size_t)node * 64 + lane];
            }
            int beg = rowptr[node], end = rowptr[node + 1];
            int e = beg;
            for (; e + 3 < end; e += 4) {
                int s0 = ssrc[e], s1 = ssrc[e + 1], s2 = ssrc[e + 2], s3 = ssrc[e + 3];
                if (XBF16) {
                    unsigned int u0 = xb2[(size_t)s0 * 64 + lane];
                    unsigned int u1 = xb2[(size_t)s1 * 64 + lane];
                    unsigned int u2 = xb2[(size_t)s2 * 64 + lane];
                    unsigned int u3 = xb2[(size_t)s3 * 64 + lane];
                    acc.x += bf2f((unsigned short)(u0 & 0xffffu)) + bf2f((unsigned short)(u1 & 0xffffu))
                           + bf2f((unsigned short)(u2 & 0xffffu)) + bf2f((unsigned short)(u3 & 0xffffu));
                    acc.y += bf2f((unsigned short)(u0 >> 16)) + bf2f((unsigned short)(u1 >> 16))
                           + bf2f((unsigned short)(u2 >> 16)) + bf2f((unsigned short)(u3 >> 16));
                } else {
                    float2 v0 = xf2[(size_t)s0 * 64 + lane];
                    float2 v1 = xf2[(size_t)s1 * 64 + lane];
                    float2 v2 = xf2[(size_t)s2 * 64 + lane];
                    float2 v3 = xf2[(size_t)s3 * 64 + lane];
                    acc.x += v0.x + v1.x + v2.x + v3.x;
                    acc.y += v0.y + v1.y + v2.y + v3.y;
                }
            }
            for (; e < end; e++) {
                int s0 = ssrc[e];
                if (XBF16) {
                    unsigned int u0 = xb2[(size_t)s0 * 64 + lane];
                    acc.x += bf2f((unsigned short)(u0 & 0xffffu));
                    acc.y += bf2f((unsigned short)(u0 >> 16));
                } else {
                    float2 v0 = xf2[(size_t)s0 * 64 + lane];
                    acc.x += v0.x;
                    acc.y += v0.y;
                }
            }
        }
        unsigned int packed = ((unsigned int)f2bf(acc.y) << 16) | (unsigned int)f2bf(acc.x);
        *((unsigned int*)&At[r][lane * 2]) = packed;
    }
    __syncthreads();

    // MFMA phase: 4 waves, wave w -> rows 16*(w&1), cols 64*(w>>1).
    int m0 = (wave & 1) * 16;
    int n0 = (wave >> 1) * 64;
    int l15 = lane & 15, q = lane >> 4;

    f32x4 acc[4];
#pragma unroll
    for (int i = 0; i < 4; i++) acc[i] = (f32x4){0.f, 0.f, 0.f, 0.f};

#pragma unroll
    for (int kc = 0; kc < 4; kc++) {
        short8 a = *((const short8*)&At[m0 + l15][kc * 32 + q * 8]);
#pragma unroll
        for (int tile = 0; tile < 4; tile++) {
            short8 b = *((const short8*)(Wb + (size_t)(n0 + 16 * tile + l15) * 128 + kc * 32 + q * 8));
            acc[tile] = __builtin_amdgcn_mfma_f32_16x16x32_bf16(a, b, acc[tile], 0, 0, 0);
        }
    }

#pragma unroll
    for (int tile = 0; tile < 4; tile++) {
        int col = n0 + 16 * tile + l15;
        float bias = b1[col];
#pragma unroll
        for (int reg = 0; reg < 4; reg++) {
            int row = q * 4 + reg;
            Ht[m0 + row][col] = fmaxf(acc[tile][reg] + bias, 0.f);
        }
    }
    __syncthreads();

    for (int i = t; i < G_ROWS * 32; i += 256) {
        int r = i >> 5, c4 = i & 31;
        int row = base + r;
        if (row < N_NODES)
            *((float4*)(hout + (size_t)row * NF + c4 * 4)) = *((const float4*)&Ht[r][c4 * 4]);
    }

    if (t < 128) {
        float s = 0.f, sq = 0.f;
        for (int r = 0; r < nrows; r++) {
            float v = Ht[r][t];
            s += v; sq += v * v;
        }
        atomicAdd(&stats[t], s);
        atomicAdd(&stats[128 + t], sq);
    }
}

// ---------------- BN fold ----------------
__global__ void finalize_bn(const float* __restrict__ stats,
                            const float* __restrict__ gamma,
                            const float* __restrict__ beta,
                            float* __restrict__ ab) {
    int f = threadIdx.x;
    if (f < 128) {
        float mean = stats[f] * (1.0f / N_NODES);
        float var = stats[128 + f] * (1.0f / N_NODES) - mean * mean;
        float rstd = rsqrtf(var + BN_EPS);
        float a = gamma[f] * rstd;
        float c = beta[f] - mean * a;
        ab[f] = a;
        ab[128 + f] = c;
    }
}

// ---------------- GEMM2 (MFMA): out = ((h*a + c) @ W2^T + b2), in-place -----
__global__ __launch_bounds__(256) void gemm2_kernel(
    float* __restrict__ h,
    const unsigned short* __restrict__ Wb,
    const float* __restrict__ b2,
    const float* __restrict__ ab) {
    __shared__ unsigned short At[G_ROWS][AP];
    __shared__ float Ht[G_ROWS][HP];

    int t = threadIdx.x;
    int base = blockIdx.x * G_ROWS;
    int nrows = N_NODES - base; if (nrows > G_ROWS) nrows = G_ROWS;

    for (int i = t; i < G_ROWS * 32; i += 256) {
        int r = i >> 5, c4 = i & 31;
        float4 v = make_float4(0.f, 0.f, 0.f, 0.f);
        if (r < nrows) {
            float4 hv = ((const float4*)(h + (size_t)(base + r) * NF))[c4];
            float4 av = ((const float4*)ab)[c4];
            float4 cv = ((const float4*)(ab + 128))[c4];
            v.x = hv.x * av.x + cv.x;
            v.y = hv.y * av.y + cv.y;
            v.z = hv.z * av.z + cv.z;
            v.w = hv.w * av.w + cv.w;
        }
        ushort4 u;
        u.x = f2bf(v.x); u.y = f2bf(v.y); u.z = f2bf(v.z); u.w = f2bf(v.w);
        *((ushort4*)&At[r][c4 * 4]) = u;
    }
    __syncthreads();

    int wave = t >> 6, lane = t & 63;
    int m0 = (wave & 1) * 16;
    int n0 = (wave >> 1) * 64;
    int l15 = lane & 15, q = lane >> 4;

    f32x4 acc[4];
#pragma unroll
    for (int i = 0; i < 4; i++) acc[i] = (f32x4){0.f, 0.f, 0.f, 0.f};

#pragma unroll
    for (int kc = 0; kc < 4; kc++) {
        short8 a = *((const short8*)&At[m0 + l15][kc * 32 + q * 8]);
#pragma unroll
        for (int tile = 0; tile < 4; tile++) {
            short8 b = *((const short8*)(Wb + (size_t)(n0 + 16 * tile + l15) * 128 + kc * 32 + q * 8));
            acc[tile] = __builtin_amdgcn_mfma_f32_16x16x32_bf16(a, b, acc[tile], 0, 0, 0);
        }
    }

#pragma unroll
    for (int tile = 0; tile < 4; tile++) {
        int col = n0 + 16 * tile + l15;
        float bias = b2[col];
#pragma unroll
        for (int reg = 0; reg < 4; reg++) {
            int row = q * 4 + reg;
            Ht[m0 + row][col] = acc[tile][reg] + bias;
        }
    }
    __syncthreads();

    for (int i = t; i < G_ROWS * 32; i += 256) {
        int r = i >> 5, c4 = i & 31;
        int row = base + r;
        if (row < N_NODES)
            *((float4*)(h + (size_t)row * NF + c4 * 4)) = *((const float4*)&Ht[r][c4 * 4]);
    }
}

extern "C" void kernel_launch(void* const* d_in, const int* in_sizes, int n_in,
                              void* d_out, int out_size, void* d_ws, size_t ws_size,
                              hipStream_t stream) {
    const float* x     = (const float*)d_in[0];
    const int*   ei    = (const int*)d_in[1];
    const float* W1    = (const float*)d_in[2];
    const float* b1    = (const float*)d_in[3];
    const float* gamma = (const float*)d_in[4];
    const float* beta  = (const float*)d_in[5];
    const float* W2    = (const float*)d_in[6];
    const float* b2    = (const float*)d_in[7];

    float* h = (float*)d_out;  // h after fused1, then final out (in-place)

    // Workspace layout
    float*          stats    = (float*)d_ws;                // 256 f
    float*          ab       = stats + 256;                 // 256 f
    unsigned short* Wb1      = (unsigned short*)(ab + 256); // 16384 us
    unsigned short* Wb2      = Wb1 + 128 * 128;             // 16384 us
    int*            counts   = (int*)(Wb2 + 128 * 128);     // 50000 i
    int*            rowptr   = counts + N_NODES;            // 50001 i
    int*            cursor   = rowptr + N_NODES + 1;        // 50000 i
    int*            partials = cursor + N_NODES;            // 256 i
    int*            ssrc     = partials + 256;              // 800000 i
    unsigned short* xb       = (unsigned short*)(ssrc + N_EDGES); // 6.4M us (optional)

    size_t need_bf16 = (size_t)((char*)(xb + (size_t)N_NODES * NF) - (char*)d_ws);
    bool use_bf16x = ws_size >= need_bf16;

    zero_kernel<<<(N_NODES + 255) / 256, 256, 0, stream>>>(counts, stats);
    prep_weights<<<64, 256, 0, stream>>>(W1, W2, Wb1, Wb2);
    hist_kernel<<<(N_EDGES + 255) / 256, 256, 0, stream>>>(ei, counts);
    scan_reduce<<<SCAN_BLOCKS, 256, 0, stream>>>(counts, partials);
    scan_partials2<<<1, 256, 0, stream>>>(partials);
    scan_apply<<<SCAN_BLOCKS, 256, 0, stream>>>(counts, partials, rowptr, cursor);
    fill_kernel<<<(N_EDGES + 255) / 256, 256, 0, stream>>>(ei, cursor, ssrc);

    int gblocks = (N_NODES + G_ROWS - 1) / G_ROWS;
    if (use_bf16x) {
        convert_x<<<(N_NODES * NF / 4 + 255) / 256, 256, 0, stream>>>(x, xb);
        fused_gather_gemm1<true><<<gblocks, 256, 0, stream>>>(
            xb, rowptr, ssrc, Wb1, b1, h, stats);
    } else {
        fused_gather_gemm1<false><<<gblocks, 256, 0, stream>>>(
            x, rowptr, ssrc, Wb1, b1, h, stats);
    }
    finalize_bn<<<1, 128, 0, stream>>>(stats, gamma, beta, ab);
    gemm2_kernel<<<gblocks, 256, 0, stream>>>(h, Wb2, b2, ab);
}

// Round 7
// 297.651 us; speedup vs baseline: 2.8422x; 1.0485x over previous
//
#include <hip/hip_runtime.h>

#define N_NODES 50000
#define N_EDGES 800000
#define NF 128
#define BN_EPS 1e-5f
#define G_ROWS 32
#define SCAN_BLOCKS ((N_NODES + 255) / 256)  // 196
#define AP 136  // bf16 A-tile pitch (shorts); 272B rows, 16B aligned
#define HP 132  // fp32 H-tile pitch

typedef __attribute__((ext_vector_type(8))) short short8;
typedef __attribute__((ext_vector_type(4))) float f32x4;

__device__ __forceinline__ unsigned short f2bf(float f) {
    union { float f; unsigned int i; } v; v.f = f;
    unsigned int r = (v.i + 0x7fffu + ((v.i >> 16) & 1u)) >> 16;
    return (unsigned short)r;
}
__device__ __forceinline__ float bf2f(unsigned short u) {
    union { unsigned int i; float f; } v; v.i = ((unsigned int)u) << 16; return v.f;
}

// ---------------- Setup: convert x->bf16 (opt), weights->bf16, zero bufs ------
#define SETUP_C (N_NODES * NF / 4)          // 1,600,000 float4->ushort4 units
#define SETUP_P (128 * 128)                 // 16,384 weight elems (both W)
#define SETUP_Z N_NODES                     // counts
#define SETUP_S 256                         // stats
__global__ void setup_kernel(const float* __restrict__ x, unsigned short* __restrict__ xb,
                             const float* __restrict__ W1, const float* __restrict__ W2,
                             unsigned short* __restrict__ Wb1, unsigned short* __restrict__ Wb2,
                             int* __restrict__ counts, float* __restrict__ stats,
                             int do_convert) {
    int i = blockIdx.x * blockDim.x + threadIdx.x;
    int off = do_convert ? 0 : SETUP_C;
    i += off;
    if (i < SETUP_C) {
        float4 v = ((const float4*)x)[i];
        ushort4 u;
        u.x = f2bf(v.x); u.y = f2bf(v.y); u.z = f2bf(v.z); u.w = f2bf(v.w);
        ((ushort4*)xb)[i] = u;
    } else if (i < SETUP_C + SETUP_P) {
        int j = i - SETUP_C;
        Wb1[j] = f2bf(W1[j]);
        Wb2[j] = f2bf(W2[j]);
    } else if (i < SETUP_C + SETUP_P + SETUP_Z) {
        counts[i - SETUP_C - SETUP_P] = 0;
    } else if (i < SETUP_C + SETUP_P + SETUP_Z + SETUP_S) {
        stats[i - SETUP_C - SETUP_P - SETUP_Z] = 0.0f;
    }
}

// ---------------- CSR build (counting sort by dst) ----------------
__global__ void hist_kernel(const int* __restrict__ ei, int* __restrict__ counts) {
    int t = blockIdx.x * blockDim.x + threadIdx.x;
    if (t < N_EDGES) atomicAdd(&counts[ei[N_EDGES + t]], 1);
}

__global__ __launch_bounds__(256) void scan_reduce(const int* __restrict__ counts,
                                                   int* __restrict__ partials) {
    __shared__ int red[256];
    int t = threadIdx.x;
    int i = blockIdx.x * 256 + t;
    red[t] = (i < N_NODES) ? counts[i] : 0;
    __syncthreads();
    for (int off = 128; off > 0; off >>= 1) {
        if (t < off) red[t] += red[t + off];
        __syncthreads();
    }
    if (t == 0) partials[blockIdx.x] = red[0];
}

__global__ __launch_bounds__(256) void scan_partials2(int* __restrict__ partials) {
    __shared__ int s[256];
    int t = threadIdx.x;
    int v = (t < SCAN_BLOCKS) ? partials[t] : 0;
    s[t] = v;
    __syncthreads();
    for (int off = 1; off < 256; off <<= 1) {
        int u = (t >= off) ? s[t - off] : 0;
        __syncthreads();
        s[t] += u;
        __syncthreads();
    }
    if (t < SCAN_BLOCKS) partials[t] = s[t] - v;  // exclusive
}

__global__ __launch_bounds__(256) void scan_apply(const int* __restrict__ counts,
                                                  const int* __restrict__ partials,
                                                  int* __restrict__ rowptr,
                                                  int* __restrict__ cursor) {
    __shared__ int s[256];
    int t = threadIdx.x;
    int i = blockIdx.x * 256 + t;
    int v = (i < N_NODES) ? counts[i] : 0;
    s[t] = v;
    __syncthreads();
    for (int off = 1; off < 256; off <<= 1) {
        int u = (t >= off) ? s[t - off] : 0;
        __syncthreads();
        s[t] += u;
        __syncthreads();
    }
    int excl = partials[blockIdx.x] + s[t] - v;
    if (i < N_NODES) {
        rowptr[i] = excl;
        cursor[i] = excl;
    }
    if (i == 0) rowptr[N_NODES] = N_EDGES;
}

__global__ void fill_kernel(const int* __restrict__ ei,
                            int* __restrict__ cursor,
                            int* __restrict__ ssrc) {
    int t = blockIdx.x * blockDim.x + threadIdx.x;
    if (t < N_EDGES) {
        int dst = ei[N_EDGES + t];
        int pos = atomicAdd(&cursor[dst], 1);
        ssrc[pos] = ei[t];
    }
}

// -------- Gather (bf16): buf[i] = bf16(x[i] + sum_{j in N(i)} x[j]) ----------
// One wave per node; lane owns 2 features (bf16x2 in one dword). fp32 accum.
__global__ __launch_bounds__(256) void gather_bf16(const unsigned short* __restrict__ xb,
                                                   const int* __restrict__ rowptr,
                                                   const int* __restrict__ ssrc,
                                                   unsigned short* __restrict__ buf) {
    int node = (blockIdx.x * blockDim.x + threadIdx.x) >> 6;
    int lane = threadIdx.x & 63;
    if (node >= N_NODES) return;
    const unsigned int* x2 = (const unsigned int*)xb;
    unsigned int u = x2[(size_t)node * 64 + lane];
    float ax = bf2f((unsigned short)(u & 0xffffu));
    float ay = bf2f((unsigned short)(u >> 16));
    int beg = rowptr[node], end = rowptr[node + 1];
    int e = beg;
    for (; e + 3 < end; e += 4) {
        int s0 = ssrc[e], s1 = ssrc[e + 1], s2 = ssrc[e + 2], s3 = ssrc[e + 3];
        unsigned int u0 = x2[(size_t)s0 * 64 + lane];
        unsigned int u1 = x2[(size_t)s1 * 64 + lane];
        unsigned int u2 = x2[(size_t)s2 * 64 + lane];
        unsigned int u3 = x2[(size_t)s3 * 64 + lane];
        ax += bf2f((unsigned short)(u0 & 0xffffu)) + bf2f((unsigned short)(u1 & 0xffffu))
            + bf2f((unsigned short)(u2 & 0xffffu)) + bf2f((unsigned short)(u3 & 0xffffu));
        ay += bf2f((unsigned short)(u0 >> 16)) + bf2f((unsigned short)(u1 >> 16))
            + bf2f((unsigned short)(u2 >> 16)) + bf2f((unsigned short)(u3 >> 16));
    }
    for (; e < end; e++) {
        unsigned int u0 = x2[(size_t)ssrc[e] * 64 + lane];
        ax += bf2f((unsigned short)(u0 & 0xffffu));
        ay += bf2f((unsigned short)(u0 >> 16));
    }
    unsigned int packed = ((unsigned int)f2bf(ay) << 16) | (unsigned int)f2bf(ax);
    ((unsigned int*)buf)[(size_t)node * 64 + lane] = packed;
}

// ------- GEMM1 (bf16 in-place): buf = bf16(relu(buf @ W1^T + b1)); BN stats --
__global__ __launch_bounds__(256) void gemm1_bf16(
    unsigned short* __restrict__ buf,
    const unsigned short* __restrict__ Wb,
    const float* __restrict__ b1,
    float* __restrict__ stats) {
    __shared__ unsigned short At[G_ROWS][AP];
    __shared__ float Ht[G_ROWS][HP];

    int t = threadIdx.x;
    int base = blockIdx.x * G_ROWS;
    int nrows = N_NODES - base; if (nrows > G_ROWS) nrows = G_ROWS;

    // Stage 32x128 bf16 tile (uint4 = 8 shorts).
    for (int i = t; i < G_ROWS * 16; i += 256) {
        int r = i >> 4, c8 = i & 15;
        uint4 v = make_uint4(0u, 0u, 0u, 0u);
        if (r < nrows) v = ((const uint4*)(buf + (size_t)(base + r) * NF))[c8];
        *((uint4*)&At[r][c8 * 8]) = v;
    }
    __syncthreads();

    int wave = t >> 6, lane = t & 63;
    int m0 = (wave & 1) * 16;
    int n0 = (wave >> 1) * 64;
    int l15 = lane & 15, q = lane >> 4;

    f32x4 acc[4];
#pragma unroll
    for (int i = 0; i < 4; i++) acc[i] = (f32x4){0.f, 0.f, 0.f, 0.f};

#pragma unroll
    for (int kc = 0; kc < 4; kc++) {
        short8 a = *((const short8*)&At[m0 + l15][kc * 32 + q * 8]);
#pragma unroll
        for (int tile = 0; tile < 4; tile++) {
            short8 b = *((const short8*)(Wb + (size_t)(n0 + 16 * tile + l15) * 128 + kc * 32 + q * 8));
            acc[tile] = __builtin_amdgcn_mfma_f32_16x16x32_bf16(a, b, acc[tile], 0, 0, 0);
        }
    }

#pragma unroll
    for (int tile = 0; tile < 4; tile++) {
        int col = n0 + 16 * tile + l15;
        float bias = b1[col];
#pragma unroll
        for (int reg = 0; reg < 4; reg++) {
            int row = q * 4 + reg;
            Ht[m0 + row][col] = fmaxf(acc[tile][reg] + bias, 0.f);
        }
    }
    __syncthreads();

    // Writeout h as bf16 (in place, same rows this block staged).
    for (int i = t; i < G_ROWS * 32; i += 256) {
        int r = i >> 5, c4 = i & 31;
        int row = base + r;
        if (row < N_NODES) {
            float4 v = *((const float4*)&Ht[r][c4 * 4]);
            ushort4 u;
            u.x = f2bf(v.x); u.y = f2bf(v.y); u.z = f2bf(v.z); u.w = f2bf(v.w);
            *((ushort4*)(buf + (size_t)row * NF + c4 * 4)) = u;
        }
    }

    // BN stats from fp32 tile.
    if (t < 128) {
        float s = 0.f, sq = 0.f;
        for (int r = 0; r < nrows; r++) {
            float v = Ht[r][t];
            s += v; sq += v * v;
        }
        atomicAdd(&stats[t], s);
        atomicAdd(&stats[128 + t], sq);
    }
}

// ---------------- BN fold ----------------
__global__ void finalize_bn(const float* __restrict__ stats,
                            const float* __restrict__ gamma,
                            const float* __restrict__ beta,
                            float* __restrict__ ab) {
    int f = threadIdx.x;
    if (f < 128) {
        float mean = stats[f] * (1.0f / N_NODES);
        float var = stats[128 + f] * (1.0f / N_NODES) - mean * mean;
        float rstd = rsqrtf(var + BN_EPS);
        float a = gamma[f] * rstd;
        float c = beta[f] - mean * a;
        ab[f] = a;
        ab[128 + f] = c;
    }
}

// -------- GEMM2 (bf16 in, fp32 out): out = ((h*a + c) @ W2^T + b2) ----------
__global__ __launch_bounds__(256) void gemm2_bf16(
    const unsigned short* __restrict__ buf,
    const unsigned short* __restrict__ Wb,
    const float* __restrict__ b2,
    const float* __restrict__ ab,
    float* __restrict__ out) {
    __shared__ unsigned short At[G_ROWS][AP];
    __shared__ float Ht[G_ROWS][HP];

    int t = threadIdx.x;
    int base = blockIdx.x * G_ROWS;
    int nrows = N_NODES - base; if (nrows > G_ROWS) nrows = G_ROWS;

    // Stage + BN affine (fp32 math, bf16 result).
    for (int i = t; i < G_ROWS * 32; i += 256) {
        int r = i >> 5, c4 = i & 31;
        ushort4 u = make_ushort4(0, 0, 0, 0);
        if (r < nrows) {
            ushort4 hv = *((const ushort4*)(buf + (size_t)(base + r) * NF + c4 * 4));
            float4 av = ((const float4*)ab)[c4];
            float4 cv = ((const float4*)(ab + 128))[c4];
            u.x = f2bf(bf2f(hv.x) * av.x + cv.x);
            u.y = f2bf(bf2f(hv.y) * av.y + cv.y);
            u.z = f2bf(bf2f(hv.z) * av.z + cv.z);
            u.w = f2bf(bf2f(hv.w) * av.w + cv.w);
        }
        *((ushort4*)&At[r][c4 * 4]) = u;
    }
    __syncthreads();

    int wave = t >> 6, lane = t & 63;
    int m0 = (wave & 1) * 16;
    int n0 = (wave >> 1) * 64;
    int l15 = lane & 15, q = lane >> 4;

    f32x4 acc[4];
#pragma unroll
    for (int i = 0; i < 4; i++) acc[i] = (f32x4){0.f, 0.f, 0.f, 0.f};

#pragma unroll
    for (int kc = 0; kc < 4; kc++) {
        short8 a = *((const short8*)&At[m0 + l15][kc * 32 + q * 8]);
#pragma unroll
        for (int tile = 0; tile < 4; tile++) {
            short8 b = *((const short8*)(Wb + (size_t)(n0 + 16 * tile + l15) * 128 + kc * 32 + q * 8));
            acc[tile] = __builtin_amdgcn_mfma_f32_16x16x32_bf16(a, b, acc[tile], 0, 0, 0);
        }
    }

#pragma unroll
    for (int tile = 0; tile < 4; tile++) {
        int col = n0 + 16 * tile + l15;
        float bias = b2[col];
#pragma unroll
        for (int reg = 0; reg < 4; reg++) {
            int row = q * 4 + reg;
            Ht[m0 + row][col] = acc[tile][reg] + bias;
        }
    }
    __syncthreads();

    for (int i = t; i < G_ROWS * 32; i += 256) {
        int r = i >> 5, c4 = i & 31;
        int row = base + r;
        if (row < N_NODES)
            *((float4*)(out + (size_t)row * NF + c4 * 4)) = *((const float4*)&Ht[r][c4 * 4]);
    }
}

// =============== Fallback path (ws too small for bf16 buffers) ===============
template <bool XBF16>
__global__ __launch_bounds__(256) void fused_gather_gemm1(
    const void* __restrict__ xv,
    const int* __restrict__ rowptr,
    const int* __restrict__ ssrc,
    const unsigned short* __restrict__ Wb,
    const float* __restrict__ b1,
    float* __restrict__ hout,
    float* __restrict__ stats) {
    __shared__ unsigned short At[G_ROWS][AP];
    __shared__ float Ht[G_ROWS][HP];

    int t = threadIdx.x;
    int wave = t >> 6, lane = t & 63;
    int base = blockIdx.x * G_ROWS;
    int nrows = N_NODES - base; if (nrows > G_ROWS) nrows = G_ROWS;

    const float2* xf2 = (const float2*)xv;

    for (int nn = 0; nn < 8; nn++) {
        int r = wave * 8 + nn;
        int node = base + r;
        float2 acc = make_float2(0.f, 0.f);
        if (node < N_NODES) {
            acc = xf2[(size_t)node * 64 + lane];
            int beg = rowptr[node], end = rowptr[node + 1];
            int e = beg;
            for (; e + 3 < end; e += 4) {
                float2 v0 = xf2[(size_t)ssrc[e] * 64 + lane];
                float2 v1 = xf2[(size_t)ssrc[e + 1] * 64 + lane];
                float2 v2 = xf2[(size_t)ssrc[e + 2] * 64 + lane];
                float2 v3 = xf2[(size_t)ssrc[e + 3] * 64 + lane];
                acc.x += v0.x + v1.x + v2.x + v3.x;
                acc.y += v0.y + v1.y + v2.y + v3.y;
            }
            for (; e < end; e++) {
                float2 v0 = xf2[(size_t)ssrc[e] * 64 + lane];
                acc.x += v0.x;
                acc.y += v0.y;
            }
        }
        unsigned int packed = ((unsigned int)f2bf(acc.y) << 16) | (unsigned int)f2bf(acc.x);
        *((unsigned int*)&At[r][lane * 2]) = packed;
    }
    __syncthreads();

    int m0 = (wave & 1) * 16;
    int n0 = (wave >> 1) * 64;
    int l15 = lane & 15, q = lane >> 4;

    f32x4 acc[4];
#pragma unroll
    for (int i = 0; i < 4; i++) acc[i] = (f32x4){0.f, 0.f, 0.f, 0.f};

#pragma unroll
    for (int kc = 0; kc < 4; kc++) {
        short8 a = *((const short8*)&At[m0 + l15][kc * 32 + q * 8]);
#pragma unroll
        for (int tile = 0; tile < 4; tile++) {
            short8 b = *((const short8*)(Wb + (size_t)(n0 + 16 * tile + l15) * 128 + kc * 32 + q * 8));
            acc[tile] = __builtin_amdgcn_mfma_f32_16x16x32_bf16(a, b, acc[tile], 0, 0, 0);
        }
    }

#pragma unroll
    for (int tile = 0; tile < 4; tile++) {
        int col = n0 + 16 * tile + l15;
        float bias = b1[col];
#pragma unroll
        for (int reg = 0; reg < 4; reg++) {
            int row = q * 4 + reg;
            Ht[m0 + row][col] = fmaxf(acc[tile][reg] + bias, 0.f);
        }
    }
    __syncthreads();

    for (int i = t; i < G_ROWS * 32; i += 256) {
        int r = i >> 5, c4 = i & 31;
        int row = base + r;
        if (row < N_NODES)
            *((float4*)(hout + (size_t)row * NF + c4 * 4)) = *((const float4*)&Ht[r][c4 * 4]);
    }

    if (t < 128) {
        float s = 0.f, sq = 0.f;
        for (int r = 0; r < nrows; r++) {
            float v = Ht[r][t];
            s += v; sq += v * v;
        }
        atomicAdd(&stats[t], s);
        atomicAdd(&stats[128 + t], sq);
    }
}

__global__ __launch_bounds__(256) void gemm2_f32(
    float* __restrict__ h,
    const unsigned short* __restrict__ Wb,
    const float* __restrict__ b2,
    const float* __restrict__ ab) {
    __shared__ unsigned short At[G_ROWS][AP];
    __shared__ float Ht[G_ROWS][HP];

    int t = threadIdx.x;
    int base = blockIdx.x * G_ROWS;
    int nrows = N_NODES - base; if (nrows > G_ROWS) nrows = G_ROWS;

    for (int i = t; i < G_ROWS * 32; i += 256) {
        int r = i >> 5, c4 = i & 31;
        float4 v = make_float4(0.f, 0.f, 0.f, 0.f);
        if (r < nrows) {
            float4 hv = ((const float4*)(h + (size_t)(base + r) * NF))[c4];
            float4 av = ((const float4*)ab)[c4];
            float4 cv = ((const float4*)(ab + 128))[c4];
            v.x = hv.x * av.x + cv.x;
            v.y = hv.y * av.y + cv.y;
            v.z = hv.z * av.z + cv.z;
            v.w = hv.w * av.w + cv.w;
        }
        ushort4 u;
        u.x = f2bf(v.x); u.y = f2bf(v.y); u.z = f2bf(v.z); u.w = f2bf(v.w);
        *((ushort4*)&At[r][c4 * 4]) = u;
    }
    __syncthreads();

    int wave = t >> 6, lane = t & 63;
    int m0 = (wave & 1) * 16;
    int n0 = (wave >> 1) * 64;
    int l15 = lane & 15, q = lane >> 4;

    f32x4 acc[4];
#pragma unroll
    for (int i = 0; i < 4; i++) acc[i] = (f32x4){0.f, 0.f, 0.f, 0.f};

#pragma unroll
    for (int kc = 0; kc < 4; kc++) {
        short8 a = *((const short8*)&At[m0 + l15][kc * 32 + q * 8]);
#pragma unroll
        for (int tile = 0; tile < 4; tile++) {
            short8 b = *((const short8*)(Wb + (size_t)(n0 + 16 * tile + l15) * 128 + kc * 32 + q * 8));
            acc[tile] = __builtin_amdgcn_mfma_f32_16x16x32_bf16(a, b, acc[tile], 0, 0, 0);
        }
    }

#pragma unroll
    for (int tile = 0; tile < 4; tile++) {
        int col = n0 + 16 * tile + l15;
        float bias = b2[col];
#pragma unroll
        for (int reg = 0; reg < 4; reg++) {
            int row = q * 4 + reg;
            Ht[m0 + row][col] = acc[tile][reg] + bias;
        }
    }
    __syncthreads();

    for (int i = t; i < G_ROWS * 32; i += 256) {
        int r = i >> 5, c4 = i & 31;
        int row = base + r;
        if (row < N_NODES)
            *((float4*)(h + (size_t)row * NF + c4 * 4)) = *((const float4*)&Ht[r][c4 * 4]);
    }
}

extern "C" void kernel_launch(void* const* d_in, const int* in_sizes, int n_in,
                              void* d_out, int out_size, void* d_ws, size_t ws_size,
                              hipStream_t stream) {
    const float* x     = (const float*)d_in[0];
    const int*   ei    = (const int*)d_in[1];
    const float* W1    = (const float*)d_in[2];
    const float* b1    = (const float*)d_in[3];
    const float* gamma = (const float*)d_in[4];
    const float* beta  = (const float*)d_in[5];
    const float* W2    = (const float*)d_in[6];
    const float* b2    = (const float*)d_in[7];

    float* out = (float*)d_out;

    // Workspace layout
    float*          stats    = (float*)d_ws;                // 256 f
    float*          ab       = stats + 256;                 // 256 f
    unsigned short* Wb1      = (unsigned short*)(ab + 256); // 16384 us
    unsigned short* Wb2      = Wb1 + 128 * 128;             // 16384 us
    int*            counts   = (int*)(Wb2 + 128 * 128);     // 50000 i
    int*            rowptr   = counts + N_NODES;            // 50001 i
    int*            cursor   = rowptr + N_NODES + 1;        // 50000 i
    int*            partials = cursor + N_NODES;            // 256 i
    int*            ssrc     = partials + 256;              // 800000 i
    unsigned short* xb       = (unsigned short*)(ssrc + N_EDGES);   // 6.4M us
    unsigned short* buf      = xb + (size_t)N_NODES * NF;           // 6.4M us

    size_t need = (size_t)((char*)(buf + (size_t)N_NODES * NF) - (char*)d_ws);
    bool bf16_path = ws_size >= need;

    int gblocks = (N_NODES + G_ROWS - 1) / G_ROWS;

    if (bf16_path) {
        int total = SETUP_C + SETUP_P + SETUP_Z + SETUP_S;
        setup_kernel<<<(total + 255) / 256, 256, 0, stream>>>(
            x, xb, W1, W2, Wb1, Wb2, counts, stats, 1);
    } else {
        int total = SETUP_P + SETUP_Z + SETUP_S;
        setup_kernel<<<(total + 255) / 256, 256, 0, stream>>>(
            x, xb, W1, W2, Wb1, Wb2, counts, stats, 0);
    }
    hist_kernel<<<(N_EDGES + 255) / 256, 256, 0, stream>>>(ei, counts);
    scan_reduce<<<SCAN_BLOCKS, 256, 0, stream>>>(counts, partials);
    scan_partials2<<<1, 256, 0, stream>>>(partials);
    scan_apply<<<SCAN_BLOCKS, 256, 0, stream>>>(counts, partials, rowptr, cursor);
    fill_kernel<<<(N_EDGES + 255) / 256, 256, 0, stream>>>(ei, cursor, ssrc);

    if (bf16_path) {
        gather_bf16<<<(N_NODES * 64) / 256, 256, 0, stream>>>(xb, rowptr, ssrc, buf);
        gemm1_bf16<<<gblocks, 256, 0, stream>>>(buf, Wb1, b1, stats);
        finalize_bn<<<1, 128, 0, stream>>>(stats, gamma, beta, ab);
        gemm2_bf16<<<gblocks, 256, 0, stream>>>(buf, Wb2, b2, ab, out);
    } else {
        fused_gather_gemm1<false><<<gblocks, 256, 0, stream>>>(
            x, rowptr, ssrc, Wb1, b1, out, stats);
        finalize_bn<<<1, 128, 0, stream>>>(stats, gamma, beta, ab);
        gemm2_f32<<<gblocks, 256, 0, stream>>>(out, Wb2, b2, ab);
    }
}

// Round 8
// 259.794 us; speedup vs baseline: 3.2564x; 1.1457x over previous
//
#include <hip/hip_runtime.h>

#define N_NODES 50000
#define N_EDGES 800000
#define NF 128
#define BN_EPS 1e-5f
#define G_ROWS 32
#define SCAN_BLOCKS ((N_NODES + 255) / 256)  // 196
#define AP 136  // bf16 A-tile pitch (shorts); 272B rows, 16B aligned
#define HP 132  // fp32 H-tile pitch

typedef __attribute__((ext_vector_type(8))) short short8;
typedef __attribute__((ext_vector_type(4))) float f32x4;

__device__ __forceinline__ unsigned short f2bf(float f) {
    union { float f; unsigned int i; } v; v.f = f;
    unsigned int r = (v.i + 0x7fffu + ((v.i >> 16) & 1u)) >> 16;
    return (unsigned short)r;
}
__device__ __forceinline__ float bf2f(unsigned short u) {
    union { unsigned int i; float f; } v; v.i = ((unsigned int)u) << 16; return v.f;
}

// ---------------- Setup: convert x->bf16 (opt), weights->bf16, zero bufs ------
#define SETUP_C (N_NODES * NF / 4)          // 1,600,000 float4->ushort4 units
#define SETUP_P (128 * 128)                 // 16,384 weight elems (both W)
#define SETUP_Z N_NODES                     // counts
#define SETUP_S 256                         // stats
__global__ void setup_kernel(const float* __restrict__ x, unsigned short* __restrict__ xb,
                             const float* __restrict__ W1, const float* __restrict__ W2,
                             unsigned short* __restrict__ Wb1, unsigned short* __restrict__ Wb2,
                             int* __restrict__ counts, float* __restrict__ stats,
                             int do_convert) {
    int i = blockIdx.x * blockDim.x + threadIdx.x;
    int off = do_convert ? 0 : SETUP_C;
    i += off;
    if (i < SETUP_C) {
        float4 v = ((const float4*)x)[i];
        ushort4 u;
        u.x = f2bf(v.x); u.y = f2bf(v.y); u.z = f2bf(v.z); u.w = f2bf(v.w);
        ((ushort4*)xb)[i] = u;
    } else if (i < SETUP_C + SETUP_P) {
        int j = i - SETUP_C;
        Wb1[j] = f2bf(W1[j]);
        Wb2[j] = f2bf(W2[j]);
    } else if (i < SETUP_C + SETUP_P + SETUP_Z) {
        counts[i - SETUP_C - SETUP_P] = 0;
    } else if (i < SETUP_C + SETUP_P + SETUP_Z + SETUP_S) {
        stats[i - SETUP_C - SETUP_P - SETUP_Z] = 0.0f;
    }
}

// ---------------- CSR build (counting sort by dst, rank-trick) ----------------
// hist: counts[dst]++ AND record each edge's rank within its dst segment.
__global__ void hist_kernel(const int* __restrict__ ei, int* __restrict__ counts,
                            int* __restrict__ rank) {
    int t = blockIdx.x * blockDim.x + threadIdx.x;
    if (t < N_EDGES) rank[t] = atomicAdd(&counts[ei[N_EDGES + t]], 1);
}

__global__ __launch_bounds__(256) void scan_reduce(const int* __restrict__ counts,
                                                   int* __restrict__ partials) {
    __shared__ int red[256];
    int t = threadIdx.x;
    int i = blockIdx.x * 256 + t;
    red[t] = (i < N_NODES) ? counts[i] : 0;
    __syncthreads();
    for (int off = 128; off > 0; off >>= 1) {
        if (t < off) red[t] += red[t + off];
        __syncthreads();
    }
    if (t == 0) partials[blockIdx.x] = red[0];
}

__global__ __launch_bounds__(256) void scan_partials2(int* __restrict__ partials) {
    __shared__ int s[256];
    int t = threadIdx.x;
    int v = (t < SCAN_BLOCKS) ? partials[t] : 0;
    s[t] = v;
    __syncthreads();
    for (int off = 1; off < 256; off <<= 1) {
        int u = (t >= off) ? s[t - off] : 0;
        __syncthreads();
        s[t] += u;
        __syncthreads();
    }
    if (t < SCAN_BLOCKS) partials[t] = s[t] - v;  // exclusive
}

__global__ __launch_bounds__(256) void scan_apply(const int* __restrict__ counts,
                                                  const int* __restrict__ partials,
                                                  int* __restrict__ rowptr) {
    __shared__ int s[256];
    int t = threadIdx.x;
    int i = blockIdx.x * 256 + t;
    int v = (i < N_NODES) ? counts[i] : 0;
    s[t] = v;
    __syncthreads();
    for (int off = 1; off < 256; off <<= 1) {
        int u = (t >= off) ? s[t - off] : 0;
        __syncthreads();
        s[t] += u;
        __syncthreads();
    }
    int excl = partials[blockIdx.x] + s[t] - v;
    if (i < N_NODES) rowptr[i] = excl;
    if (i == 0) rowptr[N_NODES] = N_EDGES;
}

// fill without atomics: position = rowptr[dst] + rank[e].
__global__ void fill_kernel(const int* __restrict__ ei,
                            const int* __restrict__ rowptr,
                            const int* __restrict__ rank,
                            int* __restrict__ ssrc) {
    int t = blockIdx.x * blockDim.x + threadIdx.x;
    if (t < N_EDGES) {
        int dst = ei[N_EDGES + t];
        ssrc[rowptr[dst] + rank[t]] = ei[t];
    }
}

// -------- Gather (bf16): buf[i] = bf16(x[i] + sum_{j in N(i)} x[j]) ----------
__global__ __launch_bounds__(256) void gather_bf16(const unsigned short* __restrict__ xb,
                                                   const int* __restrict__ rowptr,
                                                   const int* __restrict__ ssrc,
                                                   unsigned short* __restrict__ buf) {
    int node = (blockIdx.x * blockDim.x + threadIdx.x) >> 6;
    int lane = threadIdx.x & 63;
    if (node >= N_NODES) return;
    const unsigned int* x2 = (const unsigned int*)xb;
    unsigned int u = x2[(size_t)node * 64 + lane];
    float ax = bf2f((unsigned short)(u & 0xffffu));
    float ay = bf2f((unsigned short)(u >> 16));
    int beg = rowptr[node], end = rowptr[node + 1];
    int e = beg;
    for (; e + 3 < end; e += 4) {
        int s0 = ssrc[e], s1 = ssrc[e + 1], s2 = ssrc[e + 2], s3 = ssrc[e + 3];
        unsigned int u0 = x2[(size_t)s0 * 64 + lane];
        unsigned int u1 = x2[(size_t)s1 * 64 + lane];
        unsigned int u2 = x2[(size_t)s2 * 64 + lane];
        unsigned int u3 = x2[(size_t)s3 * 64 + lane];
        ax += bf2f((unsigned short)(u0 & 0xffffu)) + bf2f((unsigned short)(u1 & 0xffffu))
            + bf2f((unsigned short)(u2 & 0xffffu)) + bf2f((unsigned short)(u3 & 0xffffu));
        ay += bf2f((unsigned short)(u0 >> 16)) + bf2f((unsigned short)(u1 >> 16))
            + bf2f((unsigned short)(u2 >> 16)) + bf2f((unsigned short)(u3 >> 16));
    }
    for (; e < end; e++) {
        unsigned int u0 = x2[(size_t)ssrc[e] * 64 + lane];
        ax += bf2f((unsigned short)(u0 & 0xffffu));
        ay += bf2f((unsigned short)(u0 >> 16));
    }
    unsigned int packed = ((unsigned int)f2bf(ay) << 16) | (unsigned int)f2bf(ax);
    ((unsigned int*)buf)[(size_t)node * 64 + lane] = packed;
}

// ------- GEMM1 (bf16 in-place): buf = bf16(relu(buf @ W1^T + b1)); BN stats --
__global__ __launch_bounds__(256) void gemm1_bf16(
    unsigned short* __restrict__ buf,
    const unsigned short* __restrict__ Wb,
    const float* __restrict__ b1,
    float* __restrict__ stats) {
    __shared__ unsigned short At[G_ROWS][AP];
    __shared__ float Ht[G_ROWS][HP];

    int t = threadIdx.x;
    int base = blockIdx.x * G_ROWS;
    int nrows = N_NODES - base; if (nrows > G_ROWS) nrows = G_ROWS;

    for (int i = t; i < G_ROWS * 16; i += 256) {
        int r = i >> 4, c8 = i & 15;
        uint4 v = make_uint4(0u, 0u, 0u, 0u);
        if (r < nrows) v = ((const uint4*)(buf + (size_t)(base + r) * NF))[c8];
        *((uint4*)&At[r][c8 * 8]) = v;
    }
    __syncthreads();

    int wave = t >> 6, lane = t & 63;
    int m0 = (wave & 1) * 16;
    int n0 = (wave >> 1) * 64;
    int l15 = lane & 15, q = lane >> 4;

    f32x4 acc[4];
#pragma unroll
    for (int i = 0; i < 4; i++) acc[i] = (f32x4){0.f, 0.f, 0.f, 0.f};

#pragma unroll
    for (int kc = 0; kc < 4; kc++) {
        short8 a = *((const short8*)&At[m0 + l15][kc * 32 + q * 8]);
#pragma unroll
        for (int tile = 0; tile < 4; tile++) {
            short8 b = *((const short8*)(Wb + (size_t)(n0 + 16 * tile + l15) * 128 + kc * 32 + q * 8));
            acc[tile] = __builtin_amdgcn_mfma_f32_16x16x32_bf16(a, b, acc[tile], 0, 0, 0);
        }
    }

#pragma unroll
    for (int tile = 0; tile < 4; tile++) {
        int col = n0 + 16 * tile + l15;
        float bias = b1[col];
#pragma unroll
        for (int reg = 0; reg < 4; reg++) {
            int row = q * 4 + reg;
            Ht[m0 + row][col] = fmaxf(acc[tile][reg] + bias, 0.f);
        }
    }
    __syncthreads();

    for (int i = t; i < G_ROWS * 32; i += 256) {
        int r = i >> 5, c4 = i & 31;
        int row = base + r;
        if (row < N_NODES) {
            float4 v = *((const float4*)&Ht[r][c4 * 4]);
            ushort4 u;
            u.x = f2bf(v.x); u.y = f2bf(v.y); u.z = f2bf(v.z); u.w = f2bf(v.w);
            *((ushort4*)(buf + (size_t)row * NF + c4 * 4)) = u;
        }
    }

    if (t < 128) {
        float s = 0.f, sq = 0.f;
        for (int r = 0; r < nrows; r++) {
            float v = Ht[r][t];
            s += v; sq += v * v;
        }
        atomicAdd(&stats[t], s);
        atomicAdd(&stats[128 + t], sq);
    }
}

// ---------------- BN fold ----------------
__global__ void finalize_bn(const float* __restrict__ stats,
                            const float* __restrict__ gamma,
                            const float* __restrict__ beta,
                            float* __restrict__ ab) {
    int f = threadIdx.x;
    if (f < 128) {
        float mean = stats[f] * (1.0f / N_NODES);
        float var = stats[128 + f] * (1.0f / N_NODES) - mean * mean;
        float rstd = rsqrtf(var + BN_EPS);
        float a = gamma[f] * rstd;
        float c = beta[f] - mean * a;
        ab[f] = a;
        ab[128 + f] = c;
    }
}

// -------- GEMM2 (bf16 in, fp32 out): out = ((h*a + c) @ W2^T + b2) ----------
__global__ __launch_bounds__(256) void gemm2_bf16(
    const unsigned short* __restrict__ buf,
    const unsigned short* __restrict__ Wb,
    const float* __restrict__ b2,
    const float* __restrict__ ab,
    float* __restrict__ out) {
    __shared__ unsigned short At[G_ROWS][AP];
    __shared__ float Ht[G_ROWS][HP];

    int t = threadIdx.x;
    int base = blockIdx.x * G_ROWS;
    int nrows = N_NODES - base; if (nrows > G_ROWS) nrows = G_ROWS;

    for (int i = t; i < G_ROWS * 32; i += 256) {
        int r = i >> 5, c4 = i & 31;
        ushort4 u = make_ushort4(0, 0, 0, 0);
        if (r < nrows) {
            ushort4 hv = *((const ushort4*)(buf + (size_t)(base + r) * NF + c4 * 4));
            float4 av = ((const float4*)ab)[c4];
            float4 cv = ((const float4*)(ab + 128))[c4];
            u.x = f2bf(bf2f(hv.x) * av.x + cv.x);
            u.y = f2bf(bf2f(hv.y) * av.y + cv.y);
            u.z = f2bf(bf2f(hv.z) * av.z + cv.z);
            u.w = f2bf(bf2f(hv.w) * av.w + cv.w);
        }
        *((ushort4*)&At[r][c4 * 4]) = u;
    }
    __syncthreads();

    int wave = t >> 6, lane = t & 63;
    int m0 = (wave & 1) * 16;
    int n0 = (wave >> 1) * 64;
    int l15 = lane & 15, q = lane >> 4;

    f32x4 acc[4];
#pragma unroll
    for (int i = 0; i < 4; i++) acc[i] = (f32x4){0.f, 0.f, 0.f, 0.f};

#pragma unroll
    for (int kc = 0; kc < 4; kc++) {
        short8 a = *((const short8*)&At[m0 + l15][kc * 32 + q * 8]);
#pragma unroll
        for (int tile = 0; tile < 4; tile++) {
            short8 b = *((const short8*)(Wb + (size_t)(n0 + 16 * tile + l15) * 128 + kc * 32 + q * 8));
            acc[tile] = __builtin_amdgcn_mfma_f32_16x16x32_bf16(a, b, acc[tile], 0, 0, 0);
        }
    }

#pragma unroll
    for (int tile = 0; tile < 4; tile++) {
        int col = n0 + 16 * tile + l15;
        float bias = b2[col];
#pragma unroll
        for (int reg = 0; reg < 4; reg++) {
            int row = q * 4 + reg;
            Ht[m0 + row][col] = acc[tile][reg] + bias;
        }
    }
    __syncthreads();

    for (int i = t; i < G_ROWS * 32; i += 256) {
        int r = i >> 5, c4 = i & 31;
        int row = base + r;
        if (row < N_NODES)
            *((float4*)(out + (size_t)row * NF + c4 * 4)) = *((const float4*)&Ht[r][c4 * 4]);
    }
}

// =============== Fallback path (ws too small for bf16 buffers) ===============
__global__ __launch_bounds__(256) void fused_gather_gemm1_f32(
    const float* __restrict__ xv,
    const int* __restrict__ rowptr,
    const int* __restrict__ ssrc,
    const unsigned short* __restrict__ Wb,
    const float* __restrict__ b1,
    float* __restrict__ hout,
    float* __restrict__ stats) {
    __shared__ unsigned short At[G_ROWS][AP];
    __shared__ float Ht[G_ROWS][HP];

    int t = threadIdx.x;
    int wave = t >> 6, lane = t & 63;
    int base = blockIdx.x * G_ROWS;
    int nrows = N_NODES - base; if (nrows > G_ROWS) nrows = G_ROWS;

    const float2* xf2 = (const float2*)xv;

    for (int nn = 0; nn < 8; nn++) {
        int r = wave * 8 + nn;
        int node = base + r;
        float2 acc = make_float2(0.f, 0.f);
        if (node < N_NODES) {
            acc = xf2[(size_t)node * 64 + lane];
            int beg = rowptr[node], end = rowptr[node + 1];
            for (int e = beg; e < end; e++) {
                float2 v0 = xf2[(size_t)ssrc[e] * 64 + lane];
                acc.x += v0.x;
                acc.y += v0.y;
            }
        }
        unsigned int packed = ((unsigned int)f2bf(acc.y) << 16) | (unsigned int)f2bf(acc.x);
        *((unsigned int*)&At[r][lane * 2]) = packed;
    }
    __syncthreads();

    int m0 = (wave & 1) * 16;
    int n0 = (wave >> 1) * 64;
    int l15 = lane & 15, q = lane >> 4;

    f32x4 acc[4];
#pragma unroll
    for (int i = 0; i < 4; i++) acc[i] = (f32x4){0.f, 0.f, 0.f, 0.f};

#pragma unroll
    for (int kc = 0; kc < 4; kc++) {
        short8 a = *((const short8*)&At[m0 + l15][kc * 32 + q * 8]);
#pragma unroll
        for (int tile = 0; tile < 4; tile++) {
            short8 b = *((const short8*)(Wb + (size_t)(n0 + 16 * tile + l15) * 128 + kc * 32 + q * 8));
            acc[tile] = __builtin_amdgcn_mfma_f32_16x16x32_bf16(a, b, acc[tile], 0, 0, 0);
        }
    }

#pragma unroll
    for (int tile = 0; tile < 4; tile++) {
        int col = n0 + 16 * tile + l15;
        float bias = b1[col];
#pragma unroll
        for (int reg = 0; reg < 4; reg++) {
            int row = q * 4 + reg;
            Ht[m0 + row][col] = fmaxf(acc[tile][reg] + bias, 0.f);
        }
    }
    __syncthreads();

    for (int i = t; i < G_ROWS * 32; i += 256) {
        int r = i >> 5, c4 = i & 31;
        int row = base + r;
        if (row < N_NODES)
            *((float4*)(hout + (size_t)row * NF + c4 * 4)) = *((const float4*)&Ht[r][c4 * 4]);
    }

    if (t < 128) {
        float s = 0.f, sq = 0.f;
        for (int r = 0; r < nrows; r++) {
            float v = Ht[r][t];
            s += v; sq += v * v;
        }
        atomicAdd(&stats[t], s);
        atomicAdd(&stats[128 + t], sq);
    }
}

__global__ __launch_bounds__(256) void gemm2_f32(
    float* __restrict__ h,
    const unsigned short* __restrict__ Wb,
    const float* __restrict__ b2,
    const float* __restrict__ ab) {
    __shared__ unsigned short At[G_ROWS][AP];
    __shared__ float Ht[G_ROWS][HP];

    int t = threadIdx.x;
    int base = blockIdx.x * G_ROWS;
    int nrows = N_NODES - base; if (nrows > G_ROWS) nrows = G_ROWS;

    for (int i = t; i < G_ROWS * 32; i += 256) {
        int r = i >> 5, c4 = i & 31;
        float4 v = make_float4(0.f, 0.f, 0.f, 0.f);
        if (r < nrows) {
            float4 hv = ((const float4*)(h + (size_t)(base + r) * NF))[c4];
            float4 av = ((const float4*)ab)[c4];
            float4 cv = ((const float4*)(ab + 128))[c4];
            v.x = hv.x * av.x + cv.x;
            v.y = hv.y * av.y + cv.y;
            v.z = hv.z * av.z + cv.z;
            v.w = hv.w * av.w + cv.w;
        }
        ushort4 u;
        u.x = f2bf(v.x); u.y = f2bf(v.y); u.z = f2bf(v.z); u.w = f2bf(v.w);
        *((ushort4*)&At[r][c4 * 4]) = u;
    }
    __syncthreads();

    int wave = t >> 6, lane = t & 63;
    int m0 = (wave & 1) * 16;
    int n0 = (wave >> 1) * 64;
    int l15 = lane & 15, q = lane >> 4;

    f32x4 acc[4];
#pragma unroll
    for (int i = 0; i < 4; i++) acc[i] = (f32x4){0.f, 0.f, 0.f, 0.f};

#pragma unroll
    for (int kc = 0; kc < 4; kc++) {
        short8 a = *((const short8*)&At[m0 + l15][kc * 32 + q * 8]);
#pragma unroll
        for (int tile = 0; tile < 4; tile++) {
            short8 b = *((const short8*)(Wb + (size_t)(n0 + 16 * tile + l15) * 128 + kc * 32 + q * 8));
            acc[tile] = __builtin_amdgcn_mfma_f32_16x16x32_bf16(a, b, acc[tile], 0, 0, 0);
        }
    }

#pragma unroll
    for (int tile = 0; tile < 4; tile++) {
        int col = n0 + 16 * tile + l15;
        float bias = b2[col];
#pragma unroll
        for (int reg = 0; reg < 4; reg++) {
            int row = q * 4 + reg;
            Ht[m0 + row][col] = acc[tile][reg] + bias;
        }
    }
    __syncthreads();

    for (int i = t; i < G_ROWS * 32; i += 256) {
        int r = i >> 5, c4 = i & 31;
        int row = base + r;
        if (row < N_NODES)
            *((float4*)(h + (size_t)row * NF + c4 * 4)) = *((const float4*)&Ht[r][c4 * 4]);
    }
}

extern "C" void kernel_launch(void* const* d_in, const int* in_sizes, int n_in,
                              void* d_out, int out_size, void* d_ws, size_t ws_size,
                              hipStream_t stream) {
    const float* x     = (const float*)d_in[0];
    const int*   ei    = (const int*)d_in[1];
    const float* W1    = (const float*)d_in[2];
    const float* b1    = (const float*)d_in[3];
    const float* gamma = (const float*)d_in[4];
    const float* beta  = (const float*)d_in[5];
    const float* W2    = (const float*)d_in[6];
    const float* b2    = (const float*)d_in[7];

    float* out = (float*)d_out;

    // Workspace layout
    float*          stats    = (float*)d_ws;                // 256 f
    float*          ab       = stats + 256;                 // 256 f
    unsigned short* Wb1      = (unsigned short*)(ab + 256); // 16384 us
    unsigned short* Wb2      = Wb1 + 128 * 128;             // 16384 us
    int*            counts   = (int*)(Wb2 + 128 * 128);     // 50000 i
    int*            rowptr   = counts + N_NODES;            // 50001 i
    int*            partials = rowptr + N_NODES + 1;        // 256 i (+pad)
    int*            rank     = partials + 256;              // 800000 i
    int*            ssrc     = rank + N_EDGES;              // 800000 i
    unsigned short* xb       = (unsigned short*)(ssrc + N_EDGES);   // 6.4M us
    unsigned short* buf      = xb + (size_t)N_NODES * NF;           // 6.4M us

    size_t need = (size_t)((char*)(buf + (size_t)N_NODES * NF) - (char*)d_ws);
    bool bf16_path = ws_size >= need;

    int gblocks = (N_NODES + G_ROWS - 1) / G_ROWS;

    if (bf16_path) {
        int total = SETUP_C + SETUP_P + SETUP_Z + SETUP_S;
        setup_kernel<<<(total + 255) / 256, 256, 0, stream>>>(
            x, xb, W1, W2, Wb1, Wb2, counts, stats, 1);
    } else {
        int total = SETUP_P + SETUP_Z + SETUP_S;
        setup_kernel<<<(total + 255) / 256, 256, 0, stream>>>(
            x, xb, W1, W2, Wb1, Wb2, counts, stats, 0);
    }
    hist_kernel<<<(N_EDGES + 255) / 256, 256, 0, stream>>>(ei, counts, rank);
    scan_reduce<<<SCAN_BLOCKS, 256, 0, stream>>>(counts, partials);
    scan_partials2<<<1, 256, 0, stream>>>(partials);
    scan_apply<<<SCAN_BLOCKS, 256, 0, stream>>>(counts, partials, rowptr);
    fill_kernel<<<(N_EDGES + 255) / 256, 256, 0, stream>>>(ei, rowptr, rank, ssrc);

    if (bf16_path) {
        gather_bf16<<<(N_NODES * 64) / 256, 256, 0, stream>>>(xb, rowptr, ssrc, buf);
        gemm1_bf16<<<gblocks, 256, 0, stream>>>(buf, Wb1, b1, stats);
        finalize_bn<<<1, 128, 0, stream>>>(stats, gamma, beta, ab);
        gemm2_bf16<<<gblocks, 256, 0, stream>>>(buf, Wb2, b2, ab, out);
    } else {
        fused_gather_gemm1_f32<<<gblocks, 256, 0, stream>>>(
            x, rowptr, ssrc, Wb1, b1, out, stats);
        finalize_bn<<<1, 128, 0, stream>>>(stats, gamma, beta, ab);
        gemm2_f32<<<gblocks, 256, 0, stream>>>(out, Wb2, b2, ab);
    }
}

// Round 9
// 235.048 us; speedup vs baseline: 3.5992x; 1.1053x over previous
//
#include <hip/hip_runtime.h>

#define N_NODES 50000
#define N_EDGES 800000
#define NF 128
#define BN_EPS 1e-5f
#define G_ROWS 32
#define GBLOCKS ((N_NODES + G_ROWS - 1) / G_ROWS)   // 1563
#define NB 1568   // padded partials pitch (>= GBLOCKS, mult of 32)
#define SCAN_BLOCKS ((N_NODES + 255) / 256)  // 196
#define AP 136  // bf16 A-tile pitch (shorts); 272B rows, 16B aligned
#define HP 132  // fp32 H-tile pitch

typedef __attribute__((ext_vector_type(8))) short short8;
typedef __attribute__((ext_vector_type(4))) float f32x4;

__device__ __forceinline__ unsigned short f2bf(float f) {
    union { float f; unsigned int i; } v; v.f = f;
    unsigned int r = (v.i + 0x7fffu + ((v.i >> 16) & 1u)) >> 16;
    return (unsigned short)r;
}
__device__ __forceinline__ float bf2f(unsigned short u) {
    union { unsigned int i; float f; } v; v.i = ((unsigned int)u) << 16; return v.f;
}

// ---------------- Setup: convert x->bf16 (opt), weights->bf16, zero bufs ------
#define SETUP_C (N_NODES * NF / 4)          // 1,600,000 float4->ushort4 units
#define SETUP_P (128 * 128)                 // 16,384 weight elems (both W)
#define SETUP_Z N_NODES                     // counts
#define SETUP_S 256                         // stats (fallback path only)
__global__ void setup_kernel(const float* __restrict__ x, unsigned short* __restrict__ xb,
                             const float* __restrict__ W1, const float* __restrict__ W2,
                             unsigned short* __restrict__ Wb1, unsigned short* __restrict__ Wb2,
                             int* __restrict__ counts, float* __restrict__ stats,
                             int do_convert) {
    int i = blockIdx.x * blockDim.x + threadIdx.x;
    int off = do_convert ? 0 : SETUP_C;
    i += off;
    if (i < SETUP_C) {
        float4 v = ((const float4*)x)[i];
        ushort4 u;
        u.x = f2bf(v.x); u.y = f2bf(v.y); u.z = f2bf(v.z); u.w = f2bf(v.w);
        ((ushort4*)xb)[i] = u;
    } else if (i < SETUP_C + SETUP_P) {
        int j = i - SETUP_C;
        Wb1[j] = f2bf(W1[j]);
        Wb2[j] = f2bf(W2[j]);
    } else if (i < SETUP_C + SETUP_P + SETUP_Z) {
        counts[i - SETUP_C - SETUP_P] = 0;
    } else if (i < SETUP_C + SETUP_P + SETUP_Z + SETUP_S) {
        stats[i - SETUP_C - SETUP_P - SETUP_Z] = 0.0f;
    }
}

// ---------------- CSR build (counting sort by dst, rank-trick) ----------------
__global__ void hist_kernel(const int* __restrict__ ei, int* __restrict__ counts,
                            int* __restrict__ rank) {
    int t = blockIdx.x * blockDim.x + threadIdx.x;
    if (t < N_EDGES) rank[t] = atomicAdd(&counts[ei[N_EDGES + t]], 1);
}

__global__ __launch_bounds__(256) void scan_reduce(const int* __restrict__ counts,
                                                   int* __restrict__ partials) {
    __shared__ int red[256];
    int t = threadIdx.x;
    int i = blockIdx.x * 256 + t;
    red[t] = (i < N_NODES) ? counts[i] : 0;
    __syncthreads();
    for (int off = 128; off > 0; off >>= 1) {
        if (t < off) red[t] += red[t + off];
        __syncthreads();
    }
    if (t == 0) partials[blockIdx.x] = red[0];
}

__global__ __launch_bounds__(256) void scan_partials2(int* __restrict__ partials) {
    __shared__ int s[256];
    int t = threadIdx.x;
    int v = (t < SCAN_BLOCKS) ? partials[t] : 0;
    s[t] = v;
    __syncthreads();
    for (int off = 1; off < 256; off <<= 1) {
        int u = (t >= off) ? s[t - off] : 0;
        __syncthreads();
        s[t] += u;
        __syncthreads();
    }
    if (t < SCAN_BLOCKS) partials[t] = s[t] - v;  // exclusive
}

__global__ __launch_bounds__(256) void scan_apply(const int* __restrict__ counts,
                                                  const int* __restrict__ partials,
                                                  int* __restrict__ rowptr) {
    __shared__ int s[256];
    int t = threadIdx.x;
    int i = blockIdx.x * 256 + t;
    int v = (i < N_NODES) ? counts[i] : 0;
    s[t] = v;
    __syncthreads();
    for (int off = 1; off < 256; off <<= 1) {
        int u = (t >= off) ? s[t - off] : 0;
        __syncthreads();
        s[t] += u;
        __syncthreads();
    }
    int excl = partials[blockIdx.x] + s[t] - v;
    if (i < N_NODES) rowptr[i] = excl;
    if (i == 0) rowptr[N_NODES] = N_EDGES;
}

// fill without atomics: position = rowptr[dst] + rank[e].
__global__ void fill_kernel(const int* __restrict__ ei,
                            const int* __restrict__ rowptr,
                            const int* __restrict__ rank,
                            int* __restrict__ ssrc) {
    int t = blockIdx.x * blockDim.x + threadIdx.x;
    if (t < N_EDGES) {
        int dst = ei[N_EDGES + t];
        ssrc[rowptr[dst] + rank[t]] = ei[t];
    }
}

// -------- Gather (bf16): buf[i] = bf16(x[i] + sum_{j in N(i)} x[j]) ----------
__global__ __launch_bounds__(256) void gather_bf16(const unsigned short* __restrict__ xb,
                                                   const int* __restrict__ rowptr,
                                                   const int* __restrict__ ssrc,
                                                   unsigned short* __restrict__ buf) {
    int node = (blockIdx.x * blockDim.x + threadIdx.x) >> 6;
    int lane = threadIdx.x & 63;
    if (node >= N_NODES) return;
    const unsigned int* x2 = (const unsigned int*)xb;
    unsigned int u = x2[(size_t)node * 64 + lane];
    float ax = bf2f((unsigned short)(u & 0xffffu));
    float ay = bf2f((unsigned short)(u >> 16));
    int beg = rowptr[node], end = rowptr[node + 1];
    int e = beg;
    for (; e + 3 < end; e += 4) {
        int s0 = ssrc[e], s1 = ssrc[e + 1], s2 = ssrc[e + 2], s3 = ssrc[e + 3];
        unsigned int u0 = x2[(size_t)s0 * 64 + lane];
        unsigned int u1 = x2[(size_t)s1 * 64 + lane];
        unsigned int u2 = x2[(size_t)s2 * 64 + lane];
        unsigned int u3 = x2[(size_t)s3 * 64 + lane];
        ax += bf2f((unsigned short)(u0 & 0xffffu)) + bf2f((unsigned short)(u1 & 0xffffu))
            + bf2f((unsigned short)(u2 & 0xffffu)) + bf2f((unsigned short)(u3 & 0xffffu));
        ay += bf2f((unsigned short)(u0 >> 16)) + bf2f((unsigned short)(u1 >> 16))
            + bf2f((unsigned short)(u2 >> 16)) + bf2f((unsigned short)(u3 >> 16));
    }
    for (; e < end; e++) {
        unsigned int u0 = x2[(size_t)ssrc[e] * 64 + lane];
        ax += bf2f((unsigned short)(u0 & 0xffffu));
        ay += bf2f((unsigned short)(u0 >> 16));
    }
    unsigned int packed = ((unsigned int)f2bf(ay) << 16) | (unsigned int)f2bf(ax);
    ((unsigned int*)buf)[(size_t)node * 64 + lane] = packed;
}

// ------- GEMM1 (bf16 in-place): buf = bf16(relu(buf @ W1^T + b1)) ------------
// BN partial stats written NON-atomically to P[stat][block].
__global__ __launch_bounds__(256) void gemm1_bf16(
    unsigned short* __restrict__ buf,
    const unsigned short* __restrict__ Wb,
    const float* __restrict__ b1,
    float* __restrict__ P) {
    __shared__ unsigned short At[G_ROWS][AP];
    __shared__ float Ht[G_ROWS][HP];

    int t = threadIdx.x;
    int base = blockIdx.x * G_ROWS;
    int nrows = N_NODES - base; if (nrows > G_ROWS) nrows = G_ROWS;

    for (int i = t; i < G_ROWS * 16; i += 256) {
        int r = i >> 4, c8 = i & 15;
        uint4 v = make_uint4(0u, 0u, 0u, 0u);
        if (r < nrows) v = ((const uint4*)(buf + (size_t)(base + r) * NF))[c8];
        *((uint4*)&At[r][c8 * 8]) = v;
    }
    __syncthreads();

    int wave = t >> 6, lane = t & 63;
    int m0 = (wave & 1) * 16;
    int n0 = (wave >> 1) * 64;
    int l15 = lane & 15, q = lane >> 4;

    f32x4 acc[4];
#pragma unroll
    for (int i = 0; i < 4; i++) acc[i] = (f32x4){0.f, 0.f, 0.f, 0.f};

#pragma unroll
    for (int kc = 0; kc < 4; kc++) {
        short8 a = *((const short8*)&At[m0 + l15][kc * 32 + q * 8]);
#pragma unroll
        for (int tile = 0; tile < 4; tile++) {
            short8 b = *((const short8*)(Wb + (size_t)(n0 + 16 * tile + l15) * 128 + kc * 32 + q * 8));
            acc[tile] = __builtin_amdgcn_mfma_f32_16x16x32_bf16(a, b, acc[tile], 0, 0, 0);
        }
    }

#pragma unroll
    for (int tile = 0; tile < 4; tile++) {
        int col = n0 + 16 * tile + l15;
        float bias = b1[col];
#pragma unroll
        for (int reg = 0; reg < 4; reg++) {
            int row = q * 4 + reg;
            Ht[m0 + row][col] = fmaxf(acc[tile][reg] + bias, 0.f);
        }
    }
    __syncthreads();

    for (int i = t; i < G_ROWS * 32; i += 256) {
        int r = i >> 5, c4 = i & 31;
        int row = base + r;
        if (row < N_NODES) {
            float4 v = *((const float4*)&Ht[r][c4 * 4]);
            ushort4 u;
            u.x = f2bf(v.x); u.y = f2bf(v.y); u.z = f2bf(v.z); u.w = f2bf(v.w);
            *((ushort4*)(buf + (size_t)row * NF + c4 * 4)) = u;
        }
    }

    // Per-block BN partials: thread t<128 -> sum(feature t); t>=128 -> sumsq.
    {
        int f = t & 127;
        bool issq = (t >= 128);
        float s = 0.f;
        for (int r = 0; r < nrows; r++) {
            float v = Ht[r][f];
            s += issq ? v * v : v;
        }
        P[(size_t)t * NB + blockIdx.x] = s;
    }
}

// ------- BN reduce + fold: ab from P (no atomics) ----------------------------
__global__ __launch_bounds__(256) void bn_reduce(const float* __restrict__ P,
                                                 const float* __restrict__ gamma,
                                                 const float* __restrict__ beta,
                                                 float* __restrict__ ab) {
    __shared__ float s1[256], s2[256];
    int f = blockIdx.x;   // 0..127
    int j = threadIdx.x;
    float a = 0.f, b = 0.f;
    for (int k = j; k < GBLOCKS; k += 256) {
        a += P[(size_t)f * NB + k];
        b += P[(size_t)(128 + f) * NB + k];
    }
    s1[j] = a; s2[j] = b;
    __syncthreads();
    for (int off = 128; off > 0; off >>= 1) {
        if (j < off) { s1[j] += s1[j + off]; s2[j] += s2[j + off]; }
        __syncthreads();
    }
    if (j == 0) {
        float mean = s1[0] * (1.0f / N_NODES);
        float var = s2[0] * (1.0f / N_NODES) - mean * mean;
        float rstd = rsqrtf(var + BN_EPS);
        float aa = gamma[f] * rstd;
        float cc = beta[f] - mean * aa;
        ab[f] = aa;
        ab[128 + f] = cc;
    }
}

// -------- GEMM2 (bf16 in, fp32 out): out = ((h*a + c) @ W2^T + b2) ----------
__global__ __launch_bounds__(256) void gemm2_bf16(
    const unsigned short* __restrict__ buf,
    const unsigned short* __restrict__ Wb,
    const float* __restrict__ b2,
    const float* __restrict__ ab,
    float* __restrict__ out) {
    __shared__ unsigned short At[G_ROWS][AP];
    __shared__ float Ht[G_ROWS][HP];

    int t = threadIdx.x;
    int base = blockIdx.x * G_ROWS;
    int nrows = N_NODES - base; if (nrows > G_ROWS) nrows = G_ROWS;

    for (int i = t; i < G_ROWS * 32; i += 256) {
        int r = i >> 5, c4 = i & 31;
        ushort4 u = make_ushort4(0, 0, 0, 0);
        if (r < nrows) {
            ushort4 hv = *((const ushort4*)(buf + (size_t)(base + r) * NF + c4 * 4));
            float4 av = ((const float4*)ab)[c4];
            float4 cv = ((const float4*)(ab + 128))[c4];
            u.x = f2bf(bf2f(hv.x) * av.x + cv.x);
            u.y = f2bf(bf2f(hv.y) * av.y + cv.y);
            u.z = f2bf(bf2f(hv.z) * av.z + cv.z);
            u.w = f2bf(bf2f(hv.w) * av.w + cv.w);
        }
        *((ushort4*)&At[r][c4 * 4]) = u;
    }
    __syncthreads();

    int wave = t >> 6, lane = t & 63;
    int m0 = (wave & 1) * 16;
    int n0 = (wave >> 1) * 64;
    int l15 = lane & 15, q = lane >> 4;

    f32x4 acc[4];
#pragma unroll
    for (int i = 0; i < 4; i++) acc[i] = (f32x4){0.f, 0.f, 0.f, 0.f};

#pragma unroll
    for (int kc = 0; kc < 4; kc++) {
        short8 a = *((const short8*)&At[m0 + l15][kc * 32 + q * 8]);
#pragma unroll
        for (int tile = 0; tile < 4; tile++) {
            short8 b = *((const short8*)(Wb + (size_t)(n0 + 16 * tile + l15) * 128 + kc * 32 + q * 8));
            acc[tile] = __builtin_amdgcn_mfma_f32_16x16x32_bf16(a, b, acc[tile], 0, 0, 0);
        }
    }

#pragma unroll
    for (int tile = 0; tile < 4; tile++) {
        int col = n0 + 16 * tile + l15;
        float bias = b2[col];
#pragma unroll
        for (int reg = 0; reg < 4; reg++) {
            int row = q * 4 + reg;
            Ht[m0 + row][col] = acc[tile][reg] + bias;
        }
    }
    __syncthreads();

    for (int i = t; i < G_ROWS * 32; i += 256) {
        int r = i >> 5, c4 = i & 31;
        int row = base + r;
        if (row < N_NODES)
            *((float4*)(out + (size_t)row * NF + c4 * 4)) = *((const float4*)&Ht[r][c4 * 4]);
    }
}

// =============== Fallback path (ws too small for bf16 buffers) ===============
__global__ void finalize_bn(const float* __restrict__ stats,
                            const float* __restrict__ gamma,
                            const float* __restrict__ beta,
                            float* __restrict__ ab) {
    int f = threadIdx.x;
    if (f < 128) {
        float mean = stats[f] * (1.0f / N_NODES);
        float var = stats[128 + f] * (1.0f / N_NODES) - mean * mean;
        float rstd = rsqrtf(var + BN_EPS);
        float a = gamma[f] * rstd;
        float c = beta[f] - mean * a;
        ab[f] = a;
        ab[128 + f] = c;
    }
}

__global__ __launch_bounds__(256) void fused_gather_gemm1_f32(
    const float* __restrict__ xv,
    const int* __restrict__ rowptr,
    const int* __restrict__ ssrc,
    const unsigned short* __restrict__ Wb,
    const float* __restrict__ b1,
    float* __restrict__ hout,
    float* __restrict__ stats) {
    __shared__ unsigned short At[G_ROWS][AP];
    __shared__ float Ht[G_ROWS][HP];

    int t = threadIdx.x;
    int wave = t >> 6, lane = t & 63;
    int base = blockIdx.x * G_ROWS;
    int nrows = N_NODES - base; if (nrows > G_ROWS) nrows = G_ROWS;

    const float2* xf2 = (const float2*)xv;

    for (int nn = 0; nn < 8; nn++) {
        int r = wave * 8 + nn;
        int node = base + r;
        float2 acc = make_float2(0.f, 0.f);
        if (node < N_NODES) {
            acc = xf2[(size_t)node * 64 + lane];
            int beg = rowptr[node], end = rowptr[node + 1];
            for (int e = beg; e < end; e++) {
                float2 v0 = xf2[(size_t)ssrc[e] * 64 + lane];
                acc.x += v0.x;
                acc.y += v0.y;
            }
        }
        unsigned int packed = ((unsigned int)f2bf(acc.y) << 16) | (unsigned int)f2bf(acc.x);
        *((unsigned int*)&At[r][lane * 2]) = packed;
    }
    __syncthreads();

    int m0 = (wave & 1) * 16;
    int n0 = (wave >> 1) * 64;
    int l15 = lane & 15, q = lane >> 4;

    f32x4 acc[4];
#pragma unroll
    for (int i = 0; i < 4; i++) acc[i] = (f32x4){0.f, 0.f, 0.f, 0.f};

#pragma unroll
    for (int kc = 0; kc < 4; kc++) {
        short8 a = *((const short8*)&At[m0 + l15][kc * 32 + q * 8]);
#pragma unroll
        for (int tile = 0; tile < 4; tile++) {
            short8 b = *((const short8*)(Wb + (size_t)(n0 + 16 * tile + l15) * 128 + kc * 32 + q * 8));
            acc[tile] = __builtin_amdgcn_mfma_f32_16x16x32_bf16(a, b, acc[tile], 0, 0, 0);
        }
    }

#pragma unroll
    for (int tile = 0; tile < 4; tile++) {
        int col = n0 + 16 * tile + l15;
        float bias = b1[col];
#pragma unroll
        for (int reg = 0; reg < 4; reg++) {
            int row = q * 4 + reg;
            Ht[m0 + row][col] = fmaxf(acc[tile][reg] + bias, 0.f);
        }
    }
    __syncthreads();

    for (int i = t; i < G_ROWS * 32; i += 256) {
        int r = i >> 5, c4 = i & 31;
        int row = base + r;
        if (row < N_NODES)
            *((float4*)(hout + (size_t)row * NF + c4 * 4)) = *((const float4*)&Ht[r][c4 * 4]);
    }

    if (t < 128) {
        float s = 0.f, sq = 0.f;
        for (int r = 0; r < nrows; r++) {
            float v = Ht[r][t];
            s += v; sq += v * v;
        }
        atomicAdd(&stats[t], s);
        atomicAdd(&stats[128 + t], sq);
    }
}

__global__ __launch_bounds__(256) void gemm2_f32(
    float* __restrict__ h,
    const unsigned short* __restrict__ Wb,
    const float* __restrict__ b2,
    const float* __restrict__ ab) {
    __shared__ unsigned short At[G_ROWS][AP];
    __shared__ float Ht[G_ROWS][HP];

    int t = threadIdx.x;
    int base = blockIdx.x * G_ROWS;
    int nrows = N_NODES - base; if (nrows > G_ROWS) nrows = G_ROWS;

    for (int i = t; i < G_ROWS * 32; i += 256) {
        int r = i >> 5, c4 = i & 31;
        float4 v = make_float4(0.f, 0.f, 0.f, 0.f);
        if (r < nrows) {
            float4 hv = ((const float4*)(h + (size_t)(base + r) * NF))[c4];
            float4 av = ((const float4*)ab)[c4];
            float4 cv = ((const float4*)(ab + 128))[c4];
            v.x = hv.x * av.x + cv.x;
            v.y = hv.y * av.y + cv.y;
            v.z = hv.z * av.z + cv.z;
            v.w = hv.w * av.w + cv.w;
        }
        ushort4 u;
        u.x = f2bf(v.x); u.y = f2bf(v.y); u.z = f2bf(v.z); u.w = f2bf(v.w);
        *((ushort4*)&At[r][c4 * 4]) = u;
    }
    __syncthreads();

    int wave = t >> 6, lane = t & 63;
    int m0 = (wave & 1) * 16;
    int n0 = (wave >> 1) * 64;
    int l15 = lane & 15, q = lane >> 4;

    f32x4 acc[4];
#pragma unroll
    for (int i = 0; i < 4; i++) acc[i] = (f32x4){0.f, 0.f, 0.f, 0.f};

#pragma unroll
    for (int kc = 0; kc < 4; kc++) {
        short8 a = *((const short8*)&At[m0 + l15][kc * 32 + q * 8]);
#pragma unroll
        for (int tile = 0; tile < 4; tile++) {
            short8 b = *((const short8*)(Wb + (size_t)(n0 + 16 * tile + l15) * 128 + kc * 32 + q * 8));
            acc[tile] = __builtin_amdgcn_mfma_f32_16x16x32_bf16(a, b, acc[tile], 0, 0, 0);
        }
    }

#pragma unroll
    for (int tile = 0; tile < 4; tile++) {
        int col = n0 + 16 * tile + l15;
        float bias = b2[col];
#pragma unroll
        for (int reg = 0; reg < 4; reg++) {
            int row = q * 4 + reg;
            Ht[m0 + row][col] = acc[tile][reg] + bias;
        }
    }
    __syncthreads();

    for (int i = t; i < G_ROWS * 32; i += 256) {
        int r = i >> 5, c4 = i & 31;
        int row = base + r;
        if (row < N_NODES)
            *((float4*)(h + (size_t)row * NF + c4 * 4)) = *((const float4*)&Ht[r][c4 * 4]);
    }
}

extern "C" void kernel_launch(void* const* d_in, const int* in_sizes, int n_in,
                              void* d_out, int out_size, void* d_ws, size_t ws_size,
                              hipStream_t stream) {
    const float* x     = (const float*)d_in[0];
    const int*   ei    = (const int*)d_in[1];
    const float* W1    = (const float*)d_in[2];
    const float* b1    = (const float*)d_in[3];
    const float* gamma = (const float*)d_in[4];
    const float* beta  = (const float*)d_in[5];
    const float* W2    = (const float*)d_in[6];
    const float* b2    = (const float*)d_in[7];

    float* out = (float*)d_out;

    // Workspace layout
    float*          stats    = (float*)d_ws;                // 256 f (fallback)
    float*          ab       = stats + 256;                 // 256 f
    float*          P        = ab + 256;                    // 256*NB f (~1.6 MB)
    unsigned short* Wb1      = (unsigned short*)(P + 256 * NB); // 16384 us
    unsigned short* Wb2      = Wb1 + 128 * 128;             // 16384 us
    int*            counts   = (int*)(Wb2 + 128 * 128);     // 50000 i
    int*            rowptr   = counts + N_NODES;            // 50001 i
    int*            partials = rowptr + N_NODES + 1;        // 256 i (+pad)
    int*            rank     = partials + 256;              // 800000 i
    int*            ssrc     = rank + N_EDGES;              // 800000 i
    unsigned short* xb       = (unsigned short*)(ssrc + N_EDGES);   // 6.4M us
    unsigned short* buf      = xb + (size_t)N_NODES * NF;           // 6.4M us

    size_t need = (size_t)((char*)(buf + (size_t)N_NODES * NF) - (char*)d_ws);
    bool bf16_path = ws_size >= need;

    if (bf16_path) {
        int total = SETUP_C + SETUP_P + SETUP_Z + SETUP_S;
        setup_kernel<<<(total + 255) / 256, 256, 0, stream>>>(
            x, xb, W1, W2, Wb1, Wb2, counts, stats, 1);
    } else {
        int total = SETUP_P + SETUP_Z + SETUP_S;
        setup_kernel<<<(total + 255) / 256, 256, 0, stream>>>(
            x, xb, W1, W2, Wb1, Wb2, counts, stats, 0);
    }
    hist_kernel<<<(N_EDGES + 255) / 256, 256, 0, stream>>>(ei, counts, rank);
    scan_reduce<<<SCAN_BLOCKS, 256, 0, stream>>>(counts, partials);
    scan_partials2<<<1, 256, 0, stream>>>(partials);
    scan_apply<<<SCAN_BLOCKS, 256, 0, stream>>>(counts, partials, rowptr);
    fill_kernel<<<(N_EDGES + 255) / 256, 256, 0, stream>>>(ei, rowptr, rank, ssrc);

    if (bf16_path) {
        gather_bf16<<<(N_NODES * 64) / 256, 256, 0, stream>>>(xb, rowptr, ssrc, buf);
        gemm1_bf16<<<GBLOCKS, 256, 0, stream>>>(buf, Wb1, b1, P);
        bn_reduce<<<128, 256, 0, stream>>>(P, gamma, beta, ab);
        gemm2_bf16<<<GBLOCKS, 256, 0, stream>>>(buf, Wb2, b2, ab, out);
    } else {
        fused_gather_gemm1_f32<<<GBLOCKS, 256, 0, stream>>>(
            x, rowptr, ssrc, Wb1, b1, out, stats);
        finalize_bn<<<1, 128, 0, stream>>>(stats, gamma, beta, ab);
        gemm2_f32<<<GBLOCKS, 256, 0, stream>>>(out, Wb2, b2, ab);
    }
}